// Round 1
// baseline (21094.023 us; speedup 1.0000x reference)
//
#include <hip/hip_runtime.h>

#define TT 100
#define BB 128
#define DD 2048
#define HH 2048
#define CC 100

#define BM 16
#define BN 64
#define BK 64
#define WPAD 68   // 68 floats = 272B row stride: 16B-aligned, spreads banks

// Fused GEMM (A[M=128 x K=2048] @ W[K x N=2048] + bias) + LIF update.
// reset uses PREVIOUS membrane; mem_new = 0.9*mem + cur - reset; spike = mem_new > 1.
__global__ __launch_bounds__(256) void gemm_lif_kernel(
    const float* __restrict__ A, const float* __restrict__ W,
    const float* __restrict__ bias, float* __restrict__ mem,
    float* __restrict__ spk)
{
  __shared__ float As[BM][WPAD];
  __shared__ float Ws[BK][WPAD];
  const int tid = threadIdx.x;
  const int n0 = blockIdx.x * BN;
  const int m0 = blockIdx.y * BM;
  const int row = tid >> 4;   // 0..15  (output row within tile)
  const int cg  = tid & 15;   // 0..15  -> cols cg*4 .. cg*4+3
  float acc0 = 0.f, acc1 = 0.f, acc2 = 0.f, acc3 = 0.f;

  for (int k0 = 0; k0 < 2048; k0 += BK) {
    // stage A tile 16x64 (coalesced: 64 consecutive floats per 64 lanes)
    #pragma unroll
    for (int j = 0; j < 4; ++j) {
      int idx = tid + j * 256;
      int m = idx >> 6, k = idx & 63;
      As[m][k] = A[(m0 + m) * 2048 + k0 + k];
    }
    // stage W tile 64x64 via float4 (coalesced 16B/lane)
    #pragma unroll
    for (int j = 0; j < 4; ++j) {
      int idx = tid + j * 256;        // float4-unit index
      int k = idx >> 4, c4 = idx & 15;
      *(float4*)&Ws[k][c4 * 4] =
          *(const float4*)&W[(size_t)(k0 + k) * HH + n0 + c4 * 4];
    }
    __syncthreads();
    #pragma unroll
    for (int k = 0; k < BK; k += 4) {
      float4 a  = *(float4*)&As[row][k];
      float4 w0 = *(float4*)&Ws[k + 0][cg * 4];
      float4 w1 = *(float4*)&Ws[k + 1][cg * 4];
      float4 w2 = *(float4*)&Ws[k + 2][cg * 4];
      float4 w3 = *(float4*)&Ws[k + 3][cg * 4];
      acc0 += a.x * w0.x + a.y * w1.x + a.z * w2.x + a.w * w3.x;
      acc1 += a.x * w0.y + a.y * w1.y + a.z * w2.y + a.w * w3.y;
      acc2 += a.x * w0.z + a.y * w1.z + a.z * w2.z + a.w * w3.z;
      acc3 += a.x * w0.w + a.y * w1.w + a.z * w2.w + a.w * w3.w;
    }
    __syncthreads();
  }

  const int r = m0 + row;
  const int c = n0 + cg * 4;
  float4 bv = *(const float4*)&bias[c];
  float4 mv = *(float4*)&mem[(size_t)r * HH + c];
  float4 mnew, sp;
  {
    float cur = acc0 + bv.x, m = mv.x;
    float mn = 0.9f * m + cur - ((m > 1.0f) ? 1.0f : 0.0f);
    mnew.x = mn; sp.x = (mn > 1.0f) ? 1.0f : 0.0f;
  }
  {
    float cur = acc1 + bv.y, m = mv.y;
    float mn = 0.9f * m + cur - ((m > 1.0f) ? 1.0f : 0.0f);
    mnew.y = mn; sp.y = (mn > 1.0f) ? 1.0f : 0.0f;
  }
  {
    float cur = acc2 + bv.z, m = mv.z;
    float mn = 0.9f * m + cur - ((m > 1.0f) ? 1.0f : 0.0f);
    mnew.z = mn; sp.z = (mn > 1.0f) ? 1.0f : 0.0f;
  }
  {
    float cur = acc3 + bv.w, m = mv.w;
    float mn = 0.9f * m + cur - ((m > 1.0f) ? 1.0f : 0.0f);
    mnew.w = mn; sp.w = (mn > 1.0f) ? 1.0f : 0.0f;
  }
  *(float4*)&mem[(size_t)r * HH + c] = mnew;
  *(float4*)&spk[(size_t)r * HH + c] = sp;
}

// Output layer: s3[128x2048] @ Wo[2048x100] + bo, LIF, accumulate spikes into out.
__global__ __launch_bounds__(256) void out_layer_kernel(
    const float* __restrict__ s3, const float* __restrict__ Wo,
    const float* __restrict__ bo, float* __restrict__ memo,
    float* __restrict__ outsum)
{
  int gid = blockIdx.x * 256 + threadIdx.x;   // 0..12799 exactly
  int r = gid / CC, c = gid - r * CC;
  const float* a = s3 + (size_t)r * HH;
  float acc = 0.f;
  #pragma unroll 4
  for (int k = 0; k < HH; k += 4) {
    float4 av = *(const float4*)&a[k];
    acc += av.x * Wo[(k + 0) * CC + c] + av.y * Wo[(k + 1) * CC + c] +
           av.z * Wo[(k + 2) * CC + c] + av.w * Wo[(k + 3) * CC + c];
  }
  float cur = acc + bo[c];
  float m = memo[gid];
  float mn = 0.9f * m + cur - ((m > 1.0f) ? 1.0f : 0.0f);
  memo[gid] = mn;
  outsum[gid] += (mn > 1.0f) ? 1.0f : 0.0f;
}

__global__ void init_kernel(float* ws, int nws, float* out, int nout)
{
  int i = blockIdx.x * blockDim.x + threadIdx.x;
  int stride = gridDim.x * blockDim.x;
  for (int j = i; j < nws; j += stride) ws[j] = 0.f;
  for (int j = i; j < nout; j += stride) out[j] = 0.f;
}

extern "C" void kernel_launch(void* const* d_in, const int* in_sizes, int n_in,
                              void* d_out, int out_size, void* d_ws, size_t ws_size,
                              hipStream_t stream)
{
  const float* x  = (const float*)d_in[0];
  const float* W1 = (const float*)d_in[1];
  const float* b1 = (const float*)d_in[2];
  const float* W2 = (const float*)d_in[3];
  const float* b2 = (const float*)d_in[4];
  const float* W3 = (const float*)d_in[5];
  const float* b3 = (const float*)d_in[6];
  const float* Wo = (const float*)d_in[7];
  const float* bo = (const float*)d_in[8];
  float* out = (float*)d_out;
  float* ws  = (float*)d_ws;

  const int BH = BB * HH;            // 262144
  float* mem1 = ws;
  float* mem2 = mem1 + BH;
  float* mem3 = mem2 + BH;
  float* s1   = mem3 + BH;
  float* s2   = s1 + BH;
  float* s3   = s2 + BH;
  float* memo = s3 + BH;             // 12800 floats
  const int nws = 6 * BH + BB * CC;

  hipLaunchKernelGGL(init_kernel, dim3(512), dim3(256), 0, stream,
                     ws, nws, out, BB * CC);

  dim3 grid(HH / BN, BB / BM);       // 32 x 8 = 256 blocks
  dim3 blk(256);
  for (int t = 0; t < TT; ++t) {
    hipLaunchKernelGGL(gemm_lif_kernel, grid, blk, 0, stream,
                       x + (size_t)t * BB * DD, W1, b1, mem1, s1);
    hipLaunchKernelGGL(gemm_lif_kernel, grid, blk, 0, stream, s1, W2, b2, mem2, s2);
    hipLaunchKernelGGL(gemm_lif_kernel, grid, blk, 0, stream, s2, W3, b3, mem3, s3);
    hipLaunchKernelGGL(out_layer_kernel, dim3((BB * CC + 255) / 256), blk, 0, stream,
                       s3, Wo, bo, memo, out);
  }
}

// Round 2
// 9870.444 us; speedup vs baseline: 2.1371x; 2.1371x over previous
//
#include <hip/hip_runtime.h>

typedef short short8 __attribute__((ext_vector_type(8)));
typedef float f32x4 __attribute__((ext_vector_type(4)));
typedef int int4v __attribute__((ext_vector_type(4)));

#define TT 100
#define BB 128
#define HH 2048
#define CC 100

__device__ inline unsigned short f2bf(float f) {
  unsigned u = __float_as_uint(f);
  unsigned r = (u + 0x7FFF + ((u >> 16) & 1)) >> 16;   // RNE
  return (unsigned short)r;
}

// W[k][n] fp32 (2048x2048) -> Wt[n][k] bf16 bits
__global__ __launch_bounds__(256) void transpose_cvt(
    const float* __restrict__ W, unsigned short* __restrict__ Wt)
{
  __shared__ float t[32][33];
  int n0 = blockIdx.x * 32, k0 = blockIdx.y * 32;
  int tx = threadIdx.x, ty = threadIdx.y;   // (32,8)
  #pragma unroll
  for (int j = 0; j < 4; ++j)
    t[ty + 8 * j][tx] = W[(size_t)(k0 + ty + 8 * j) * HH + n0 + tx];
  __syncthreads();
  #pragma unroll
  for (int j = 0; j < 4; ++j)
    Wt[(size_t)(n0 + ty + 8 * j) * HH + k0 + tx] = f2bf(t[tx][ty + 8 * j]);
}

// Fused bf16-MFMA GEMM (A[128xK] @ W[KxN] via Wt[n][k]) + LIF.
// BM=16 BN=32 BK=128; block=128 thr (2 waves, 16x16 tile each); grid (64,8).
template <bool AFP32>
__global__ __launch_bounds__(128) void gemm_lif(
    const void* __restrict__ Av, const unsigned short* __restrict__ Wt,
    const float* __restrict__ bias, float* __restrict__ mem,
    unsigned short* __restrict__ spk)
{
  __shared__ unsigned short As[16 * 128];  // 4KB: row stride 256B, k-swizzled
  __shared__ unsigned short Bs[32 * 128];  // 8KB
  const int tid = threadIdx.x;
  const int w = tid >> 6, l = tid & 63;
  const int n0 = blockIdx.x * 32;
  const int m0 = blockIdx.y * 16;
  f32x4 acc = {0.f, 0.f, 0.f, 0.f};

  for (int k0 = 0; k0 < 2048; k0 += 128) {
    // ---- stage A: 256 granules of 16B, 2 per thread
    #pragma unroll
    for (int i = 0; i < 2; ++i) {
      int g = tid + i * 128;
      int m = g >> 4, gi = g & 15;
      int kb = (gi * 16) ^ ((m & 7) << 4);   // swizzled byte offset in row
      if (AFP32) {
        const float* src = (const float*)Av + (size_t)(m0 + m) * HH + k0 + (kb >> 1);
        float4 f0 = *(const float4*)src;
        float4 f1 = *(const float4*)(src + 4);
        short8 pv;
        pv[0] = (short)f2bf(f0.x); pv[1] = (short)f2bf(f0.y);
        pv[2] = (short)f2bf(f0.z); pv[3] = (short)f2bf(f0.w);
        pv[4] = (short)f2bf(f1.x); pv[5] = (short)f2bf(f1.y);
        pv[6] = (short)f2bf(f1.z); pv[7] = (short)f2bf(f1.w);
        *(short8*)&As[g * 8] = pv;
      } else {
        const char* src = (const char*)((const unsigned short*)Av +
                          (size_t)(m0 + m) * HH + k0) + kb;
        *(int4v*)&As[g * 8] = *(const int4v*)src;
      }
    }
    // ---- stage B: 512 granules, 4 per thread
    #pragma unroll
    for (int i = 0; i < 4; ++i) {
      int g = tid + i * 128;
      int n = g >> 4, gi = g & 15;
      int kb = (gi * 16) ^ ((n & 7) << 4);
      const char* src = (const char*)(Wt + (size_t)(n0 + n) * HH + k0) + kb;
      *(int4v*)&Bs[g * 8] = *(const int4v*)src;
    }
    __syncthreads();
    #pragma unroll
    for (int kk = 0; kk < 4; ++kk) {
      int mr = l & 15, g = l >> 4;
      int ab = mr * 256 + (((kk * 4 + g) * 16) ^ ((mr & 7) << 4));
      int nr = w * 16 + (l & 15);
      int bb = nr * 256 + (((kk * 4 + g) * 16) ^ ((nr & 7) << 4));
      short8 a = *(short8*)((char*)As + ab);
      short8 b = *(short8*)((char*)Bs + bb);
      acc = __builtin_amdgcn_mfma_f32_16x16x32_bf16(a, b, acc, 0, 0, 0);
    }
    __syncthreads();
  }

  // ---- LIF epilogue (C/D: col = lane&15, row = (lane>>4)*4 + j)
  int col = n0 + w * 16 + (l & 15);
  int rbase = m0 + (l >> 4) * 4;
  float bv = bias[col];
  #pragma unroll
  for (int j = 0; j < 4; ++j) {
    int idx = (rbase + j) * HH + col;
    float cur = acc[j] + bv;
    float mo = mem[idx];
    float mn = 0.9f * mo + cur - ((mo > 1.0f) ? 1.0f : 0.0f);
    mem[idx] = mn;
    spk[idx] = (mn > 1.0f) ? (unsigned short)0x3F80 : (unsigned short)0;
  }
}

// Output layer: s3[128x2048](bf16 spikes) @ Wo[2048x100] + bo, LIF, spike-sum.
// One block per row r; 512 thr: c = tid&127, k-slice = tid>>7 (4 slices of 512).
__global__ __launch_bounds__(512) void out_lif(
    const unsigned short* __restrict__ s3, const float* __restrict__ Wo,
    const float* __restrict__ bo, float* __restrict__ memo,
    float* __restrict__ outsum)
{
  __shared__ float red[512];
  int r = blockIdx.x;
  int tid = threadIdx.x;
  int c = tid & 127, ks = tid >> 7;
  const unsigned short* a = s3 + (size_t)r * HH + ks * 512;
  float acc = 0.f;
  if (c < CC) {
    const float* wseg = Wo + (size_t)(ks * 512) * CC + c;
    for (int k = 0; k < 512; ++k) {
      if (a[k]) acc += wseg[k * CC];   // spike==1.0 exactly; uniform branch
    }
  }
  red[tid] = acc;
  __syncthreads();
  if (ks == 0 && c < CC) {
    float total = red[c] + red[c + 128] + red[c + 256] + red[c + 384];
    int idx = r * CC + c;
    float cur = total + bo[c];
    float mo = memo[idx];
    float mn = 0.9f * mo + cur - ((mo > 1.0f) ? 1.0f : 0.0f);
    memo[idx] = mn;
    outsum[idx] += (mn > 1.0f) ? 1.0f : 0.0f;
  }
}

__global__ void init_kernel(float* z, int nz, float* out, int nout)
{
  int i = blockIdx.x * blockDim.x + threadIdx.x;
  int stride = gridDim.x * blockDim.x;
  for (int j = i; j < nz; j += stride) z[j] = 0.f;
  for (int j = i; j < nout; j += stride) out[j] = 0.f;
}

extern "C" void kernel_launch(void* const* d_in, const int* in_sizes, int n_in,
                              void* d_out, int out_size, void* d_ws, size_t ws_size,
                              hipStream_t stream)
{
  const float* x  = (const float*)d_in[0];
  const float* W1 = (const float*)d_in[1];
  const float* b1 = (const float*)d_in[2];
  const float* W2 = (const float*)d_in[3];
  const float* b2 = (const float*)d_in[4];
  const float* W3 = (const float*)d_in[5];
  const float* b3 = (const float*)d_in[6];
  const float* Wo = (const float*)d_in[7];
  const float* bo = (const float*)d_in[8];
  float* out = (float*)d_out;

  const int BH = BB * HH;                  // 262144
  float* mem1 = (float*)d_ws;
  float* mem2 = mem1 + BH;
  float* mem3 = mem2 + BH;
  float* memo = mem3 + BH;                 // 12800 floats
  unsigned short* s1  = (unsigned short*)(memo + BB * CC);
  unsigned short* s2  = s1 + BH;
  unsigned short* s3  = s2 + BH;
  unsigned short* Wt1 = s3 + BH;
  unsigned short* Wt2 = Wt1 + (size_t)HH * HH;
  unsigned short* Wt3 = Wt2 + (size_t)HH * HH;

  hipLaunchKernelGGL(init_kernel, dim3(512), dim3(256), 0, stream,
                     mem1, 3 * BH + BB * CC, out, BB * CC);

  dim3 tg(64, 64), tb(32, 8);
  hipLaunchKernelGGL(transpose_cvt, tg, tb, 0, stream, W1, Wt1);
  hipLaunchKernelGGL(transpose_cvt, tg, tb, 0, stream, W2, Wt2);
  hipLaunchKernelGGL(transpose_cvt, tg, tb, 0, stream, W3, Wt3);

  dim3 grid(HH / 32, BB / 16);             // (64, 8) = 512 blocks
  dim3 blk(128);
  for (int t = 0; t < TT; ++t) {
    hipLaunchKernelGGL((gemm_lif<true>), grid, blk, 0, stream,
                       (const void*)(x + (size_t)t * BB * HH), Wt1, b1, mem1, s1);
    hipLaunchKernelGGL((gemm_lif<false>), grid, blk, 0, stream,
                       (const void*)s1, Wt2, b2, mem2, s2);
    hipLaunchKernelGGL((gemm_lif<false>), grid, blk, 0, stream,
                       (const void*)s2, Wt3, b3, mem3, s3);
    hipLaunchKernelGGL(out_lif, dim3(BB), dim3(512), 0, stream,
                       s3, Wo, bo, memo, out);
  }
}

// Round 3
// 6718.172 us; speedup vs baseline: 3.1398x; 1.4692x over previous
//
#include <hip/hip_runtime.h>

typedef short short8 __attribute__((ext_vector_type(8)));
typedef float f32x4 __attribute__((ext_vector_type(4)));
typedef int int4v __attribute__((ext_vector_type(4)));

#define TT 100
#define BB 128
#define HH 2048
#define CC 100

__device__ inline unsigned short f2bf(float f) {
  unsigned u = __float_as_uint(f);
  return (unsigned short)((u + 0x7FFF + ((u >> 16) & 1)) >> 16);  // RNE
}
__device__ inline float bf2f(unsigned short b) {
  return __uint_as_float((unsigned)b << 16);
}

// W[k][n] fp32 (2048x2048) -> Wt[n][k] bf16 bits
__global__ __launch_bounds__(256) void transpose_cvt(
    const float* __restrict__ W, unsigned short* __restrict__ Wt)
{
  __shared__ float t[32][33];
  int n0 = blockIdx.x * 32, k0 = blockIdx.y * 32;
  int tx = threadIdx.x, ty = threadIdx.y;   // (32,8)
  #pragma unroll
  for (int j = 0; j < 4; ++j)
    t[ty + 8 * j][tx] = W[(size_t)(k0 + ty + 8 * j) * HH + n0 + tx];
  __syncthreads();
  #pragma unroll
  for (int j = 0; j < 4; ++j)
    Wt[(size_t)(n0 + ty + 8 * j) * HH + k0 + tx] = f2bf(t[tx][ty + 8 * j]);
}

// Big hoisted GEMM: cur1[M x 2048] = A(fp32)[M x 2048] @ W + bias, bf16 out.
// BM=BN=64, BK=128, 256 thr (4 waves, 2x2 of 32x32-wave-tiles of 2x2 frags).
__global__ __launch_bounds__(256) void gemm_big(
    const float* __restrict__ A, const unsigned short* __restrict__ Wt,
    const float* __restrict__ bias, unsigned short* __restrict__ cur)
{
  __shared__ unsigned short As[64 * 128];   // 16KB, 256B rows, swizzled
  __shared__ unsigned short Bs[64 * 128];   // 16KB
  const int tid = threadIdx.x;
  const int w = tid >> 6, l = tid & 63;
  const int wm = w & 1, wn = w >> 1;
  const int n0 = blockIdx.x * 64, m0 = blockIdx.y * 64;
  f32x4 acc[2][2] = {};

  for (int k0 = 0; k0 < 2048; k0 += 128) {
    #pragma unroll
    for (int i = 0; i < 4; ++i) {
      int g = tid + i * 256;               // 0..1023
      int r = g >> 4, gi = g & 15;
      int kb = (gi * 16) ^ ((r & 7) << 4);
      const float* src = A + (size_t)(m0 + r) * HH + k0 + (kb >> 1);
      float4 f0 = *(const float4*)src, f1 = *(const float4*)(src + 4);
      short8 pv;
      pv[0] = (short)f2bf(f0.x); pv[1] = (short)f2bf(f0.y);
      pv[2] = (short)f2bf(f0.z); pv[3] = (short)f2bf(f0.w);
      pv[4] = (short)f2bf(f1.x); pv[5] = (short)f2bf(f1.y);
      pv[6] = (short)f2bf(f1.z); pv[7] = (short)f2bf(f1.w);
      *(int4v*)((char*)As + r * 256 + kb) = *(int4v*)&pv;
      const char* bsrc = (const char*)(Wt + (size_t)(n0 + r) * HH + k0) + kb;
      *(int4v*)((char*)Bs + r * 256 + kb) = *(const int4v*)bsrc;
    }
    __syncthreads();
    #pragma unroll
    for (int kk = 0; kk < 4; ++kk) {
      int koff = (kk * 4 + (l >> 4)) * 16;
      short8 a[2], b[2];
      #pragma unroll
      for (int mi = 0; mi < 2; ++mi) {
        int mr = wm * 32 + mi * 16 + (l & 15);
        a[mi] = *(short8*)((char*)As + mr * 256 + (koff ^ ((mr & 7) << 4)));
      }
      #pragma unroll
      for (int ni = 0; ni < 2; ++ni) {
        int nr = wn * 32 + ni * 16 + (l & 15);
        b[ni] = *(short8*)((char*)Bs + nr * 256 + (koff ^ ((nr & 7) << 4)));
      }
      #pragma unroll
      for (int mi = 0; mi < 2; ++mi)
        #pragma unroll
        for (int ni = 0; ni < 2; ++ni)
          acc[mi][ni] = __builtin_amdgcn_mfma_f32_16x16x32_bf16(
              a[mi], b[ni], acc[mi][ni], 0, 0, 0);
    }
    __syncthreads();
  }
  #pragma unroll
  for (int mi = 0; mi < 2; ++mi)
    #pragma unroll
    for (int ni = 0; ni < 2; ++ni) {
      int col = n0 + wn * 32 + ni * 16 + (l & 15);
      int rbase = m0 + wm * 32 + mi * 16 + (l >> 4) * 4;
      float bv = bias[col];
      #pragma unroll
      for (int j = 0; j < 4; ++j)
        cur[(size_t)(rbase + j) * HH + col] = f2bf(acc[mi][ni][j] + bv);
    }
}

// Per-step fused GEMM+LIF. A[128x2048] @ W[2048x2048] + bias -> LIF.
// BM=32 BN=64 BK=128, 256 thr (4 waves, wave tile 16x32).
// Register-prefetch pipeline: issue global loads for tile t+1 before MFMA of t.
template <bool AFP32>
__global__ __launch_bounds__(256) void gemm_lif(
    const void* __restrict__ Av, const unsigned short* __restrict__ Wt,
    const float* __restrict__ bias, float* __restrict__ mem,
    unsigned short* __restrict__ spk)
{
  __shared__ unsigned short As[32 * 128];   // 8KB
  __shared__ unsigned short Bs[64 * 128];   // 16KB
  const int tid = threadIdx.x;
  const int w = tid >> 6, l = tid & 63;
  const int wm = w & 1, wn = w >> 1;
  const int n0 = blockIdx.x * 64, m0 = blockIdx.y * 32;
  f32x4 acc[2] = {};
  int4v pa[2], pb[4];

  // addressing helpers (recomputed each use; cheap VALU)
  auto loadA = [&](int k0) {
    #pragma unroll
    for (int i = 0; i < 2; ++i) {
      int g = tid + i * 256;               // 0..511
      int r = g >> 4, gi = g & 15;
      int kb = (gi * 16) ^ ((r & 7) << 4);
      if (AFP32) {
        const float* src = (const float*)Av + (size_t)(m0 + r) * HH + k0 + (kb >> 1);
        float4 f0 = *(const float4*)src, f1 = *(const float4*)(src + 4);
        short8 pv;
        pv[0] = (short)f2bf(f0.x); pv[1] = (short)f2bf(f0.y);
        pv[2] = (short)f2bf(f0.z); pv[3] = (short)f2bf(f0.w);
        pv[4] = (short)f2bf(f1.x); pv[5] = (short)f2bf(f1.y);
        pv[6] = (short)f2bf(f1.z); pv[7] = (short)f2bf(f1.w);
        pa[i] = *(int4v*)&pv;
      } else {
        const char* src = (const char*)((const unsigned short*)Av +
                           (size_t)(m0 + r) * HH + k0) + kb;
        pa[i] = *(const int4v*)src;
      }
    }
  };
  auto loadB = [&](int k0) {
    #pragma unroll
    for (int i = 0; i < 4; ++i) {
      int g = tid + i * 256;               // 0..1023
      int r = g >> 4, gi = g & 15;
      int kb = (gi * 16) ^ ((r & 7) << 4);
      const char* src = (const char*)(Wt + (size_t)(n0 + r) * HH + k0) + kb;
      pb[i] = *(const int4v*)src;
    }
  };
  auto storeRegs = [&]() {
    #pragma unroll
    for (int i = 0; i < 2; ++i) {
      int g = tid + i * 256;
      int r = g >> 4, gi = g & 15;
      int kb = (gi * 16) ^ ((r & 7) << 4);
      *(int4v*)((char*)As + r * 256 + kb) = pa[i];
    }
    #pragma unroll
    for (int i = 0; i < 4; ++i) {
      int g = tid + i * 256;
      int r = g >> 4, gi = g & 15;
      int kb = (gi * 16) ^ ((r & 7) << 4);
      *(int4v*)((char*)Bs + r * 256 + kb) = pb[i];
    }
  };

  loadA(0); loadB(0);
  storeRegs();
  __syncthreads();

  for (int it = 0; it < 16; ++it) {
    if (it < 15) { loadA((it + 1) * 128); loadB((it + 1) * 128); }
    #pragma unroll
    for (int kk = 0; kk < 4; ++kk) {
      int koff = (kk * 4 + (l >> 4)) * 16;
      int mr = wm * 16 + (l & 15);
      short8 a = *(short8*)((char*)As + mr * 256 + (koff ^ ((mr & 7) << 4)));
      #pragma unroll
      for (int ni = 0; ni < 2; ++ni) {
        int nr = wn * 32 + ni * 16 + (l & 15);
        short8 b = *(short8*)((char*)Bs + nr * 256 + (koff ^ ((nr & 7) << 4)));
        acc[ni] = __builtin_amdgcn_mfma_f32_16x16x32_bf16(a, b, acc[ni], 0, 0, 0);
      }
    }
    __syncthreads();
    if (it < 15) {
      storeRegs();          // compiler inserts vmcnt waits before these writes
      __syncthreads();
    }
  }

  #pragma unroll
  for (int ni = 0; ni < 2; ++ni) {
    int col = n0 + wn * 32 + ni * 16 + (l & 15);
    int rbase = m0 + wm * 16 + (l >> 4) * 4;
    float bv = bias[col];
    #pragma unroll
    for (int j = 0; j < 4; ++j) {
      int idx = (rbase + j) * HH + col;
      float cur = acc[ni][j] + bv;
      float mo = mem[idx];
      float mn = 0.9f * mo + cur - ((mo > 1.0f) ? 1.0f : 0.0f);
      mem[idx] = mn;
      spk[idx] = (mn > 1.0f) ? (unsigned short)0x3F80 : (unsigned short)0;
    }
  }
}

// Fused tail: blocks [0,128) do output layer for step t (s3 @ Wo + LIF + sum);
// blocks [128,192) do layer-1 LIF for step t+1 from precomputed cur1.
__global__ __launch_bounds__(512) void fused_tail(
    const unsigned short* __restrict__ s3, const float* __restrict__ Wo,
    const float* __restrict__ bo, float* __restrict__ memo,
    float* __restrict__ outsum,
    const unsigned short* __restrict__ cur1_t, float* __restrict__ mem1,
    unsigned short* __restrict__ s1, int do_out, int do_lif1)
{
  __shared__ float red[512];
  int b = blockIdx.x;
  int tid = threadIdx.x;
  if (b < 128) {
    if (!do_out) return;
    int r = b;
    int c = tid & 127, ks = tid >> 7;
    const unsigned short* a = s3 + (size_t)r * HH + ks * 512;
    float acc = 0.f;
    if (c < CC) {
      const float* wseg = Wo + (size_t)(ks * 512) * CC + c;
      for (int k = 0; k < 512; ++k) {
        if (a[k]) acc += wseg[k * CC];    // spike == 1.0 exactly
      }
    }
    red[tid] = acc;
    __syncthreads();
    if (ks == 0 && c < CC) {
      float total = red[c] + red[c + 128] + red[c + 256] + red[c + 384];
      int idx = r * CC + c;
      float cur = total + bo[c];
      float mo = memo[idx];
      float mn = 0.9f * mo + cur - ((mo > 1.0f) ? 1.0f : 0.0f);
      memo[idx] = mn;
      outsum[idx] += (mn > 1.0f) ? 1.0f : 0.0f;
    }
  } else {
    if (!do_lif1) return;
    int idx = (b - 128) * 512 + tid;      // 0..32767, 8 elems each
    short8 cv = *(const short8*)&cur1_t[(size_t)idx * 8];
    f32x4 mlo = *(f32x4*)&mem1[(size_t)idx * 8];
    f32x4 mhi = *(f32x4*)&mem1[(size_t)idx * 8 + 4];
    short8 sp;
    #pragma unroll
    for (int j = 0; j < 8; ++j) {
      float cur = bf2f((unsigned short)cv[j]);
      float mo = (j < 4) ? mlo[j] : mhi[j - 4];
      float mn = 0.9f * mo + cur - ((mo > 1.0f) ? 1.0f : 0.0f);
      if (j < 4) mlo[j] = mn; else mhi[j - 4] = mn;
      sp[j] = (mn > 1.0f) ? (short)0x3F80 : (short)0;
    }
    *(f32x4*)&mem1[(size_t)idx * 8] = mlo;
    *(f32x4*)&mem1[(size_t)idx * 8 + 4] = mhi;
    *(short8*)&s1[(size_t)idx * 8] = sp;
  }
}

__global__ void init_kernel(float* z, int nz, float* out, int nout)
{
  int i = blockIdx.x * blockDim.x + threadIdx.x;
  int stride = gridDim.x * blockDim.x;
  for (int j = i; j < nz; j += stride) z[j] = 0.f;
  for (int j = i; j < nout; j += stride) out[j] = 0.f;
}

extern "C" void kernel_launch(void* const* d_in, const int* in_sizes, int n_in,
                              void* d_out, int out_size, void* d_ws, size_t ws_size,
                              hipStream_t stream)
{
  const float* x  = (const float*)d_in[0];
  const float* W1 = (const float*)d_in[1];
  const float* b1 = (const float*)d_in[2];
  const float* W2 = (const float*)d_in[3];
  const float* b2 = (const float*)d_in[4];
  const float* W3 = (const float*)d_in[5];
  const float* b3 = (const float*)d_in[6];
  const float* Wo = (const float*)d_in[7];
  const float* bo = (const float*)d_in[8];
  float* out = (float*)d_out;

  const int BH = BB * HH;                       // 262144
  float* mem1 = (float*)d_ws;
  float* mem2 = mem1 + BH;
  float* mem3 = mem2 + BH;
  float* memo = mem3 + BH;                      // 12800 floats
  unsigned short* s1  = (unsigned short*)(memo + BB * CC);
  unsigned short* s2  = s1 + BH;
  unsigned short* s3  = s2 + BH;
  unsigned short* Wt1 = s3 + BH;
  unsigned short* Wt2 = Wt1 + (size_t)HH * HH;
  unsigned short* Wt3 = Wt2 + (size_t)HH * HH;
  unsigned short* cur1 = Wt3 + (size_t)HH * HH; // 12800 x 2048 bf16
  size_t need = ((char*)(cur1 + (size_t)TT * BH) - (char*)d_ws);
  bool hoist = ws_size >= need;

  hipLaunchKernelGGL(init_kernel, dim3(512), dim3(256), 0, stream,
                     mem1, 3 * BH + BB * CC, out, BB * CC);

  dim3 tg(64, 64), tb(32, 8);
  hipLaunchKernelGGL(transpose_cvt, tg, tb, 0, stream, W1, Wt1);
  hipLaunchKernelGGL(transpose_cvt, tg, tb, 0, stream, W2, Wt2);
  hipLaunchKernelGGL(transpose_cvt, tg, tb, 0, stream, W3, Wt3);

  dim3 gblk(256);
  dim3 sgrid(HH / 64, BB / 32);                 // (32, 4) = 128 blocks
  dim3 tailg(192), tailb(512);

  if (hoist) {
    hipLaunchKernelGGL(gemm_big, dim3(HH / 64, (TT * BB) / 64), gblk, 0, stream,
                       x, Wt1, b1, cur1);
    // layer-1 LIF for t=0
    hipLaunchKernelGGL(fused_tail, tailg, tailb, 0, stream,
                       s3, Wo, bo, memo, out, cur1, mem1, s1, 0, 1);
    for (int t = 0; t < TT; ++t) {
      hipLaunchKernelGGL((gemm_lif<false>), sgrid, gblk, 0, stream,
                         (const void*)s1, Wt2, b2, mem2, s2);
      hipLaunchKernelGGL((gemm_lif<false>), sgrid, gblk, 0, stream,
                         (const void*)s2, Wt3, b3, mem3, s3);
      const unsigned short* cnext = (t < TT - 1) ? cur1 + (size_t)(t + 1) * BH : cur1;
      hipLaunchKernelGGL(fused_tail, tailg, tailb, 0, stream,
                         s3, Wo, bo, memo, out, cnext, mem1, s1,
                         1, (t < TT - 1) ? 1 : 0);
    }
  } else {
    for (int t = 0; t < TT; ++t) {
      hipLaunchKernelGGL((gemm_lif<true>), sgrid, gblk, 0, stream,
                         (const void*)(x + (size_t)t * BB * HH), Wt1, b1, mem1, s1);
      hipLaunchKernelGGL((gemm_lif<false>), sgrid, gblk, 0, stream,
                         (const void*)s1, Wt2, b2, mem2, s2);
      hipLaunchKernelGGL((gemm_lif<false>), sgrid, gblk, 0, stream,
                         (const void*)s2, Wt3, b3, mem3, s3);
      hipLaunchKernelGGL(fused_tail, tailg, tailb, 0, stream,
                         s3, Wo, bo, memo, out, cur1, mem1, s1, 1, 0);
    }
  }
}

// Round 4
// 5295.570 us; speedup vs baseline: 3.9833x; 1.2686x over previous
//
#include <hip/hip_runtime.h>

typedef short short8 __attribute__((ext_vector_type(8)));
typedef short short4v __attribute__((ext_vector_type(4)));
typedef float f32x4 __attribute__((ext_vector_type(4)));
typedef int int4v __attribute__((ext_vector_type(4)));

#define TT 100
#define BB 128
#define HH 2048
#define CC 100
#define NBLK 132

__device__ inline unsigned short f2bf(float f) {
  unsigned u = __float_as_uint(f);
  return (unsigned short)((u + 0x7FFF + ((u >> 16) & 1)) >> 16);  // RNE
}
__device__ inline float bf2f(unsigned short b) {
  return __uint_as_float((unsigned)b << 16);
}

// W[k][n] fp32 (2048x2048) -> Wt[n][k] bf16 bits (for gemm_big / W1 only)
__global__ __launch_bounds__(256) void transpose_cvt(
    const float* __restrict__ W, unsigned short* __restrict__ Wt)
{
  __shared__ float t[32][33];
  int n0 = blockIdx.x * 32, k0 = blockIdx.y * 32;
  int tx = threadIdx.x, ty = threadIdx.y;   // (32,8)
  #pragma unroll
  for (int j = 0; j < 4; ++j)
    t[ty + 8 * j][tx] = W[(size_t)(k0 + ty + 8 * j) * HH + n0 + tx];
  __syncthreads();
  #pragma unroll
  for (int j = 0; j < 4; ++j)
    Wt[(size_t)(n0 + ty + 8 * j) * HH + k0 + tx] = f2bf(t[tx][ty + 8 * j]);
}

// Hoisted layer-1 GEMM: cur1[12800 x 2048] = x(fp32) @ W1 + b1, bf16 out.
__global__ __launch_bounds__(256) void gemm_big(
    const float* __restrict__ A, const unsigned short* __restrict__ Wt,
    const float* __restrict__ bias, unsigned short* __restrict__ cur)
{
  __shared__ unsigned short As[64 * 128];
  __shared__ unsigned short Bs[64 * 128];
  const int tid = threadIdx.x;
  const int w = tid >> 6, l = tid & 63;
  const int wm = w & 1, wn = w >> 1;
  const int n0 = blockIdx.x * 64, m0 = blockIdx.y * 64;
  f32x4 acc[2][2] = {};

  for (int k0 = 0; k0 < 2048; k0 += 128) {
    #pragma unroll
    for (int i = 0; i < 4; ++i) {
      int g = tid + i * 256;
      int r = g >> 4, gi = g & 15;
      int kb = (gi * 16) ^ ((r & 7) << 4);
      const float* src = A + (size_t)(m0 + r) * HH + k0 + (kb >> 1);
      float4 f0 = *(const float4*)src, f1 = *(const float4*)(src + 4);
      short8 pv;
      pv[0] = (short)f2bf(f0.x); pv[1] = (short)f2bf(f0.y);
      pv[2] = (short)f2bf(f0.z); pv[3] = (short)f2bf(f0.w);
      pv[4] = (short)f2bf(f1.x); pv[5] = (short)f2bf(f1.y);
      pv[6] = (short)f2bf(f1.z); pv[7] = (short)f2bf(f1.w);
      *(int4v*)((char*)As + r * 256 + kb) = *(int4v*)&pv;
      const char* bsrc = (const char*)(Wt + (size_t)(n0 + r) * HH + k0) + kb;
      *(int4v*)((char*)Bs + r * 256 + kb) = *(const int4v*)bsrc;
    }
    __syncthreads();
    #pragma unroll
    for (int kk = 0; kk < 4; ++kk) {
      int koff = (kk * 4 + (l >> 4)) * 16;
      short8 a[2], b[2];
      #pragma unroll
      for (int mi = 0; mi < 2; ++mi) {
        int mr = wm * 32 + mi * 16 + (l & 15);
        a[mi] = *(short8*)((char*)As + mr * 256 + (koff ^ ((mr & 7) << 4)));
      }
      #pragma unroll
      for (int ni = 0; ni < 2; ++ni) {
        int nr = wn * 32 + ni * 16 + (l & 15);
        b[ni] = *(short8*)((char*)Bs + nr * 256 + (koff ^ ((nr & 7) << 4)));
      }
      #pragma unroll
      for (int mi = 0; mi < 2; ++mi)
        #pragma unroll
        for (int ni = 0; ni < 2; ++ni)
          acc[mi][ni] = __builtin_amdgcn_mfma_f32_16x16x32_bf16(
              a[mi], b[ni], acc[mi][ni], 0, 0, 0);
    }
    __syncthreads();
  }
  #pragma unroll
  for (int mi = 0; mi < 2; ++mi)
    #pragma unroll
    for (int ni = 0; ni < 2; ++ni) {
      int col = n0 + wn * 32 + ni * 16 + (l & 15);
      int rbase = m0 + wm * 32 + mi * 16 + (l >> 4) * 4;
      float bv = bias[col];
      #pragma unroll
      for (int j = 0; j < 4; ++j)
        cur[(size_t)(rbase + j) * HH + col] = f2bf(acc[mi][ni][j] + bv);
    }
}

__global__ void init_kernel(float* z, int nz, float* out, int nout)
{
  int i = blockIdx.x * blockDim.x + threadIdx.x;
  int stride = gridDim.x * blockDim.x;
  for (int j = i; j < nz; j += stride) z[j] = 0.f;
  for (int j = i; j < nout; j += stride) out[j] = 0.f;
}

// generation grid barrier; bar[0]=counter, bar[1]=generation
__device__ inline void gbar(unsigned* bar)
{
  __syncthreads();
  if (threadIdx.x == 0) {
    __threadfence();   // release: publish this block's writes agent-wide
    unsigned g = __hip_atomic_load(&bar[1], __ATOMIC_RELAXED, __HIP_MEMORY_SCOPE_AGENT);
    unsigned a = __hip_atomic_fetch_add(&bar[0], 1u, __ATOMIC_ACQ_REL, __HIP_MEMORY_SCOPE_AGENT);
    if (a == (unsigned)(NBLK - 1)) {
      __hip_atomic_store(&bar[0], 0u, __ATOMIC_RELAXED, __HIP_MEMORY_SCOPE_AGENT);
      __hip_atomic_store(&bar[1], g + 1u, __ATOMIC_RELEASE, __HIP_MEMORY_SCOPE_AGENT);
    } else {
      while (__hip_atomic_load(&bar[1], __ATOMIC_ACQUIRE, __HIP_MEMORY_SCOPE_AGENT) == g)
        __builtin_amdgcn_s_sleep(2);
    }
    __threadfence();   // acquire: invalidate stale cached lines
  }
  __syncthreads();
}

// Persistent SNN kernel: 132 blocks x 512 thr (8 waves), 1 block/CU.
// Blocks 0..63: layer2 (32 cols each); 64..127: layer3; 128..131: out layer.
// Weight panel [32 n][2048 k] bf16 XOR-swizzled, LDS-resident for all steps.
// Waves: km=w>>1 (K quarter), wm=w&1 (64-row half). Split-K reduce in LDS.
__global__ __launch_bounds__(512, 1) void snn_persist(
    const unsigned short* __restrict__ cur1,
    const float* __restrict__ W2, const float* __restrict__ b2,
    const float* __restrict__ W3, const float* __restrict__ b3,
    const float* __restrict__ Wo, const float* __restrict__ bo,
    float* __restrict__ mem1, float* __restrict__ mem2,
    float* __restrict__ mem3, float* __restrict__ memo,
    unsigned short* s1, unsigned short* s2, unsigned short* s3,
    float* __restrict__ outsum, unsigned* bar)
{
  extern __shared__ char smem[];                 // 128KB panel + 16KB scratch
  float* scratch = (float*)(smem + 131072);

  const int blk = blockIdx.x;
  const int tid = threadIdx.x;
  const int w = tid >> 6, l = tid & 63;
  const int km = w >> 1, wm = w & 1;

  int role, n0c, ldw;
  const float *Wsrc, *bias;
  float* mem;
  if (blk < 64)       { role = 0; Wsrc = W2; bias = b2; ldw = HH; n0c = blk * 32;        mem = mem2; }
  else if (blk < 128) { role = 1; Wsrc = W3; bias = b3; ldw = HH; n0c = (blk - 64) * 32; mem = mem3; }
  else                { role = 2; Wsrc = Wo; bias = bo; ldw = CC; n0c = (blk - 128) * 32; mem = memo; }

  // ---- one-time panel load: panel[n][k] bf16, swizzled byte = n*4096 + (2k ^ ((n&7)<<4))
  {
    int n = tid & 31, kg = tid >> 5;             // kg 0..15
    bool valid = (role != 2) || (n0c + n < CC);
    for (int j = 0; j < 128; ++j) {
      int k = j * 16 + kg;
      float v = valid ? Wsrc[(size_t)k * ldw + n0c + n] : 0.f;
      *(unsigned short*)(smem + n * 4096 + ((2 * k) ^ ((n & 7) << 4))) = f2bf(v);
    }
  }
  __syncthreads();

  for (int p = 0; p <= TT + 2; ++p) {
    // ---- layer-1 LIF slice (row = blk), step p
    if (blk < BB && p < TT) {
      int e = blk * HH + tid * 4;
      short4v cv = *(const short4v*)&cur1[(size_t)p * BB * HH + e];
      f32x4 mv = *(f32x4*)&mem1[e];
      short4v sp;
      #pragma unroll
      for (int j = 0; j < 4; ++j) {
        float c = bf2f((unsigned short)cv[j]);
        float mo = mv[j];
        float mn = 0.9f * mo + c - ((mo > 1.f) ? 1.f : 0.f);
        mv[j] = mn;
        sp[j] = (mn > 1.f) ? (short)0x3F80 : (short)0;
      }
      *(f32x4*)&mem1[e] = mv;
      *(short4v*)&s1[(size_t)(p & 1) * BB * HH + e] = sp;
    }

    // ---- GEMM+LIF phase: role r processes step t = p-1-r
    int t = p - 1 - role;
    if (t >= 0 && t < TT) {
      const unsigned short* sin;
      unsigned short* sout = 0;
      if (role == 0)      { sin = s1 + (size_t)(t & 1) * BB * HH; sout = s2 + (size_t)(t & 1) * BB * HH; }
      else if (role == 1) { sin = s2 + (size_t)(t & 1) * BB * HH; sout = s3 + (size_t)(t & 1) * BB * HH; }
      else                { sin = s3 + (size_t)(t & 1) * BB * HH; }

      f32x4 acc[4][2] = {};
      const unsigned short* aptr[4];
      #pragma unroll
      for (int mi = 0; mi < 4; ++mi)
        aptr[mi] = sin + (size_t)(wm * 64 + mi * 16 + (l & 15)) * HH + km * 512 + (l >> 4) * 8;

      int4v abuf[2][4];
      #pragma unroll
      for (int mi = 0; mi < 4; ++mi) abuf[0][mi] = *(const int4v*)(aptr[mi]);
      #pragma unroll
      for (int mi = 0; mi < 4; ++mi) abuf[1][mi] = *(const int4v*)(aptr[mi] + 32);

      #pragma unroll 2
      for (int s = 0; s < 16; ++s) {
        short8 av[4], bv[2];
        #pragma unroll
        for (int mi = 0; mi < 4; ++mi) av[mi] = *(short8*)&abuf[s & 1][mi];
        if (s < 14) {
          #pragma unroll
          for (int mi = 0; mi < 4; ++mi)
            abuf[s & 1][mi] = *(const int4v*)(aptr[mi] + (s + 2) * 32);
        }
        #pragma unroll
        for (int ni = 0; ni < 2; ++ni) {
          int n = ni * 16 + (l & 15);
          int byt = n * 4096 + ((km * 1024 + s * 64 + ((l >> 4) * 16)) ^ ((n & 7) << 4));
          bv[ni] = *(short8*)(smem + byt);
        }
        #pragma unroll
        for (int mi = 0; mi < 4; ++mi)
          #pragma unroll
          for (int ni = 0; ni < 2; ++ni)
            acc[mi][ni] = __builtin_amdgcn_mfma_f32_16x16x32_bf16(
                av[mi], bv[ni], acc[mi][ni], 0, 0, 0);
      }

      // split-K reduce: km 1,2,3 accumulate into scratch, km 0 finishes
      __syncthreads();
      if (km == 1) {
        #pragma unroll
        for (int mi = 0; mi < 4; ++mi)
          #pragma unroll
          for (int ni = 0; ni < 2; ++ni)
            *(f32x4*)&scratch[(((wm * 4 + mi) * 2 + ni) * 256 + l * 4)] = acc[mi][ni];
      }
      __syncthreads();
      if (km == 2) {
        #pragma unroll
        for (int mi = 0; mi < 4; ++mi)
          #pragma unroll
          for (int ni = 0; ni < 2; ++ni) {
            int si = (((wm * 4 + mi) * 2 + ni) * 256 + l * 4);
            *(f32x4*)&scratch[si] = *(f32x4*)&scratch[si] + acc[mi][ni];
          }
      }
      __syncthreads();
      if (km == 3) {
        #pragma unroll
        for (int mi = 0; mi < 4; ++mi)
          #pragma unroll
          for (int ni = 0; ni < 2; ++ni) {
            int si = (((wm * 4 + mi) * 2 + ni) * 256 + l * 4);
            *(f32x4*)&scratch[si] = *(f32x4*)&scratch[si] + acc[mi][ni];
          }
      }
      __syncthreads();
      if (km == 0) {
        #pragma unroll
        for (int mi = 0; mi < 4; ++mi)
          #pragma unroll
          for (int ni = 0; ni < 2; ++ni) {
            f32x4 a4 = acc[mi][ni] +
                       *(f32x4*)&scratch[(((wm * 4 + mi) * 2 + ni) * 256 + l * 4)];
            int nl = ni * 16 + (l & 15);
            int colg = n0c + nl;
            float bv2 = (role == 2) ? ((colg < CC) ? bias[colg] : 0.f) : bias[colg];
            int rbase = wm * 64 + mi * 16 + (l >> 4) * 4;
            #pragma unroll
            for (int j = 0; j < 4; ++j) {
              int r = rbase + j;
              float curv = a4[j] + bv2;
              if (role == 2) {
                int midx = r * 128 + (blk - 128) * 32 + nl;
                float mo = mem[midx];
                float mn = 0.9f * mo + curv - ((mo > 1.f) ? 1.f : 0.f);
                mem[midx] = mn;
                if (colg < CC && mn > 1.f) outsum[r * CC + colg] += 1.f;
              } else {
                int idx = r * HH + colg;
                float mo = mem[idx];
                float mn = 0.9f * mo + curv - ((mo > 1.f) ? 1.f : 0.f);
                mem[idx] = mn;
                sout[idx] = (mn > 1.f) ? (unsigned short)0x3F80 : (unsigned short)0;
              }
            }
          }
      }
    }

    gbar(bar);
  }
}

extern "C" void kernel_launch(void* const* d_in, const int* in_sizes, int n_in,
                              void* d_out, int out_size, void* d_ws, size_t ws_size,
                              hipStream_t stream)
{
  const float* x  = (const float*)d_in[0];
  const float* W1 = (const float*)d_in[1];
  const float* b1 = (const float*)d_in[2];
  const float* W2 = (const float*)d_in[3];
  const float* b2 = (const float*)d_in[4];
  const float* W3 = (const float*)d_in[5];
  const float* b3 = (const float*)d_in[6];
  const float* Wo = (const float*)d_in[7];
  const float* bo = (const float*)d_in[8];
  float* out = (float*)d_out;

  const int BH = BB * HH;                         // 262144
  float* mem1 = (float*)d_ws;
  float* mem2 = mem1 + BH;
  float* mem3 = mem2 + BH;
  float* memo = mem3 + BH;                        // 128*128 padded
  unsigned* bar = (unsigned*)(memo + BB * 128);   // 64 uints
  unsigned short* s1  = (unsigned short*)(bar + 64);
  unsigned short* s2  = s1 + 2 * BH;
  unsigned short* s3  = s2 + 2 * BH;
  unsigned short* Wt1 = s3 + 2 * BH;
  unsigned short* cur1 = Wt1 + (size_t)HH * HH;   // 100*128*2048 bf16

  const int nz = 3 * BH + BB * 128 + 64;          // mem1..memo + bar

  hipFuncSetAttribute((const void*)snn_persist,
                      hipFuncAttributeMaxDynamicSharedMemorySize, 147456);

  hipLaunchKernelGGL(init_kernel, dim3(512), dim3(256), 0, stream,
                     (float*)d_ws, nz, out, BB * CC);
  hipLaunchKernelGGL(transpose_cvt, dim3(64, 64), dim3(32, 8), 0, stream, W1, Wt1);
  hipLaunchKernelGGL(gemm_big, dim3(HH / 64, (TT * BB) / 64), dim3(256), 0, stream,
                     x, Wt1, b1, cur1);
  hipLaunchKernelGGL(snn_persist, dim3(NBLK), dim3(512), 147456, stream,
                     cur1, W2, b2, W3, b3, Wo, bo,
                     mem1, mem2, mem3, memo, s1, s2, s3, out, bar);
}

// Round 6
// 2477.589 us; speedup vs baseline: 8.5139x; 2.1374x over previous
//
#include <hip/hip_runtime.h>

typedef short short8 __attribute__((ext_vector_type(8)));
typedef float f32x4 __attribute__((ext_vector_type(4)));
typedef int int4v __attribute__((ext_vector_type(4)));
typedef unsigned uint4v __attribute__((ext_vector_type(4)));

#define TT 100
#define BB 128
#define HH 2048
#define CC 100
#define NBLK 132

__device__ inline unsigned short f2bf(float f) {
  unsigned u = __float_as_uint(f);
  return (unsigned short)((u + 0x7FFF + ((u >> 16) & 1)) >> 16);  // RNE
}
__device__ inline float bf2f(unsigned short b) {
  return __uint_as_float((unsigned)b << 16);
}

// W[k][n] fp32 (2048x2048) -> Wt[n][k] bf16 bits (for gemm_big / W1 only)
__global__ __launch_bounds__(256) void transpose_cvt(
    const float* __restrict__ W, unsigned short* __restrict__ Wt)
{
  __shared__ float t[32][33];
  int n0 = blockIdx.x * 32, k0 = blockIdx.y * 32;
  int tx = threadIdx.x, ty = threadIdx.y;   // (32,8)
  #pragma unroll
  for (int j = 0; j < 4; ++j)
    t[ty + 8 * j][tx] = W[(size_t)(k0 + ty + 8 * j) * HH + n0 + tx];
  __syncthreads();
  #pragma unroll
  for (int j = 0; j < 4; ++j)
    Wt[(size_t)(n0 + ty + 8 * j) * HH + k0 + tx] = f2bf(t[tx][ty + 8 * j]);
}

// Hoisted layer-1 GEMM: cur1[12800 x 2048] = x(fp32) @ W1 + b1, bf16 out.
__global__ __launch_bounds__(256) void gemm_big(
    const float* __restrict__ A, const unsigned short* __restrict__ Wt,
    const float* __restrict__ bias, unsigned short* __restrict__ cur)
{
  __shared__ unsigned short As[128 * 128];   // 32KB
  __shared__ unsigned short Bs[64 * 128];    // 16KB
  const int tid = threadIdx.x;
  const int w = tid >> 6, l = tid & 63;
  const int wm = w & 1, wn = w >> 1;
  const int c16 = l & 15, g = l >> 4;
  const int n0 = blockIdx.x * 64, m0 = blockIdx.y * 128;
  f32x4 acc[4][2] = {};

  for (int k0 = 0; k0 < 2048; k0 += 128) {
    #pragma unroll
    for (int i = 0; i < 8; ++i) {
      int gg = tid + i * 256;
      int r = gg >> 4, gi = gg & 15;
      int kb = (gi * 16) ^ ((r & 7) << 4);
      const float* src = A + (size_t)(m0 + r) * HH + k0 + (kb >> 1);
      float4 f0 = *(const float4*)src, f1 = *(const float4*)(src + 4);
      short8 pv;
      pv[0] = (short)f2bf(f0.x); pv[1] = (short)f2bf(f0.y);
      pv[2] = (short)f2bf(f0.z); pv[3] = (short)f2bf(f0.w);
      pv[4] = (short)f2bf(f1.x); pv[5] = (short)f2bf(f1.y);
      pv[6] = (short)f2bf(f1.z); pv[7] = (short)f2bf(f1.w);
      *(int4v*)((char*)As + r * 256 + kb) = *(int4v*)&pv;
    }
    #pragma unroll
    for (int i = 0; i < 4; ++i) {
      int gg = tid + i * 256;
      int r = gg >> 4, gi = gg & 15;
      int kb = (gi * 16) ^ ((r & 7) << 4);
      const char* bsrc = (const char*)(Wt + (size_t)(n0 + r) * HH + k0) + kb;
      *(int4v*)((char*)Bs + r * 256 + kb) = *(const int4v*)bsrc;
    }
    __syncthreads();
    #pragma unroll
    for (int kk = 0; kk < 4; ++kk) {
      int koff = (kk * 4 + g) * 16;
      short8 a[4], b[2];
      #pragma unroll
      for (int mi = 0; mi < 4; ++mi) {
        int mr = wm * 64 + mi * 16 + c16;
        a[mi] = *(short8*)((char*)As + mr * 256 + (koff ^ ((mr & 7) << 4)));
      }
      #pragma unroll
      for (int ni = 0; ni < 2; ++ni) {
        int nr = wn * 32 + ni * 16 + c16;
        b[ni] = *(short8*)((char*)Bs + nr * 256 + (koff ^ ((nr & 7) << 4)));
      }
      #pragma unroll
      for (int mi = 0; mi < 4; ++mi)
        #pragma unroll
        for (int ni = 0; ni < 2; ++ni)
          acc[mi][ni] = __builtin_amdgcn_mfma_f32_16x16x32_bf16(
              a[mi], b[ni], acc[mi][ni], 0, 0, 0);
    }
    __syncthreads();
  }
  #pragma unroll
  for (int mi = 0; mi < 4; ++mi)
    #pragma unroll
    for (int ni = 0; ni < 2; ++ni) {
      int col = n0 + wn * 32 + ni * 16 + c16;
      int rbase = m0 + wm * 64 + mi * 16 + g * 4;
      float bv = bias[col];
      #pragma unroll
      for (int j = 0; j < 4; ++j)
        cur[(size_t)(rbase + j) * HH + col] = f2bf(acc[mi][ni][j] + bv);
    }
}

__global__ void init_kernel(unsigned* bar, int nbar, float* out, int nout)
{
  int i = blockIdx.x * blockDim.x + threadIdx.x;
  int stride = gridDim.x * blockDim.x;
  for (int j = i; j < nbar; j += stride) bar[j] = 0u;
  for (int j = i; j < nout; j += stride) out[j] = 0.f;
}

// Symmetric flag-array grid barrier, round-4-proven orderings, bounded spin.
__device__ inline void gbar(unsigned* flags, unsigned gen)
{
  __syncthreads();
  if (threadIdx.x == 0) {
    __threadfence();   // acq_rel agent: flush this block's dirty L2 lines
    __hip_atomic_store(&flags[blockIdx.x * 32], gen, __ATOMIC_RELEASE,
                       __HIP_MEMORY_SCOPE_AGENT);
  }
  if (threadIdx.x < NBLK) {
    int guard = 0;
    while (__hip_atomic_load(&flags[threadIdx.x * 32], __ATOMIC_ACQUIRE,
                             __HIP_MEMORY_SCOPE_AGENT) < gen) {
      __builtin_amdgcn_s_sleep(2);
      if (++guard > (1 << 22)) break;   // safety: deadlock -> bounded wrong run
    }
  }
  __syncthreads();
}

// Persistent SNN kernel: 132 blocks x 512 thr (8 waves), 1 block/CU.
// Blocks 0..63: layer2; 64..127: layer3; 128..131: out layer (32 cols each).
// Weight panel [32 n][2048 k] bf16 XOR-swizzled, LDS-resident for all steps.
// Membranes + output spike-sums in registers. Spikes = 1-bit masks in ws.
// Waves: km=w>>2 (K half), wm=w&3 (32-row quarter). Split-K reduce in LDS.
__global__ __launch_bounds__(512, 1) void snn_persist(
    const unsigned short* __restrict__ cur1,
    const float* __restrict__ W2, const float* __restrict__ b2,
    const float* __restrict__ W3, const float* __restrict__ b3,
    const float* __restrict__ Wo, const float* __restrict__ bo,
    unsigned* __restrict__ s1b, unsigned* __restrict__ s2b,
    unsigned* __restrict__ s3b,
    float* __restrict__ outsum, unsigned* __restrict__ flags)
{
  extern __shared__ char smem[];                 // 128KB panel + 16KB scratch
  float* scratch = (float*)(smem + 131072);

  const int blk = blockIdx.x;
  const int tid = threadIdx.x;
  const int w = tid >> 6, l = tid & 63;
  const int km = w >> 2, wm = w & 3;
  const int c16 = l & 15, g = l >> 4;

  int role, n0c, ldw;
  const float *Wsrc, *bias;
  if (blk < 64)       { role = 0; Wsrc = W2; bias = b2; ldw = HH; n0c = blk * 32; }
  else if (blk < 128) { role = 1; Wsrc = W3; bias = b3; ldw = HH; n0c = (blk - 64) * 32; }
  else                { role = 2; Wsrc = Wo; bias = bo; ldw = CC; n0c = (blk - 128) * 32; }

  // ---- one-time panel load: panel[n][k] bf16, byte = n*4096 + (2k ^ ((n&7)<<4))
  {
    int n = tid & 31, kg = tid >> 5;             // kg 0..15
    bool valid = (role != 2) || (n0c + n < CC);
    for (int j = 0; j < 128; ++j) {
      int k = j * 16 + kg;
      float v = valid ? Wsrc[(size_t)k * ldw + n0c + n] : 0.f;
      *(unsigned short*)(smem + n * 4096 + ((2 * k) ^ ((n & 7) << 4))) = f2bf(v);
    }
  }
  __syncthreads();

  // per-lane B addressing: base_n ^ (s*64) gives swizzled byte offset
  int basep[2];
  #pragma unroll
  for (int ni = 0; ni < 2; ++ni) {
    int n = ni * 16 + c16;
    int swn = (n & 7) << 4;
    basep[ni] = n * 4096 + km * 2048 + ((g * 16) ^ (swn & 48)) + (swn & 64);
  }
  float bv2[2];
  #pragma unroll
  for (int ni = 0; ni < 2; ++ni) {
    int colg = n0c + ni * 16 + c16;
    bv2[ni] = (role == 2) ? ((colg < CC) ? bias[colg] : 0.f) : bias[colg];
  }
  const int gb = g * 8;

  f32x4 m1reg = {0.f, 0.f, 0.f, 0.f};           // layer-1 membrane (blocks<128)
  f32x4 memb[2][2] = {};                        // role membranes (km0 waves)
  float osum[2][2][4] = {};                     // out-layer spike counts (km0)

  for (int p = 0; p <= TT + 2; ++p) {
    const unsigned gen = (unsigned)(p + 1);

    // ---- layer-1 LIF slice (row = blk), step p; pack spikes to bits
    if (blk < BB && p < TT) {
      const unsigned* cp = (const unsigned*)(cur1 + (size_t)p * BB * HH +
                                             (size_t)blk * HH + tid * 4);
      unsigned c0 = cp[0], c1 = cp[1];
      float cv[4] = { bf2f((unsigned short)(c0 & 0xFFFF)),
                      bf2f((unsigned short)(c0 >> 16)),
                      bf2f((unsigned short)(c1 & 0xFFFF)),
                      bf2f((unsigned short)(c1 >> 16)) };
      unsigned nib = 0;
      #pragma unroll
      for (int j = 0; j < 4; ++j) {
        float mo = m1reg[j];
        float mn = 0.9f * mo + cv[j] - ((mo > 1.f) ? 1.f : 0.f);
        m1reg[j] = mn;
        nib |= (mn > 1.f ? 1u : 0u) << j;
      }
      ((unsigned char*)scratch)[tid] = (unsigned char)nib;
      __syncthreads();
      if (tid < 64) {
        unsigned u0 = ((unsigned*)scratch)[tid * 2];
        unsigned u1 = ((unsigned*)scratch)[tid * 2 + 1];
        u0 = (u0 | (u0 >> 4)) & 0x00FF00FFu; u0 = (u0 | (u0 >> 8)) & 0x0000FFFFu;
        u1 = (u1 | (u1 >> 4)) & 0x00FF00FFu; u1 = (u1 | (u1 >> 8)) & 0x0000FFFFu;
        s1b[(size_t)(p & 1) * BB * 64 + blk * 64 + tid] = u0 | (u1 << 16);
      }
    }

    // ---- GEMM+LIF phase: role r processes step t = p-1-r
    int t = p - 1 - role;
    if (t >= 0 && t < TT) {
      const unsigned* sinb = (role == 0 ? s1b : role == 1 ? s2b : s3b) +
                             (size_t)(t & 1) * BB * 64;
      unsigned* soutb = (role == 0 ? s2b : s3b) + (size_t)(t & 1) * BB * 64;

      f32x4 acc[2][2] = {};
      // rows: mi=0 -> wm*32 + c16 ; mi=1 -> +16. words: row*64 + km*32 + s
      const unsigned* rp0 = sinb + (wm * 32 + c16) * 64 + km * 32;
      const unsigned* rp1 = rp0 + 16 * 64;
      int4v ca[2], cb[2];                        // rolling dwordx4 chunks
      ca[0] = *(const int4v*)(rp0);  ca[1] = *(const int4v*)(rp0 + 4);
      cb[0] = *(const int4v*)(rp1);  cb[1] = *(const int4v*)(rp1 + 4);

      #pragma unroll
      for (int s = 0; s < 32; ++s) {
        const int cc = s >> 2, slot = cc & 1, wi = s & 3;
        unsigned aw0 = (unsigned)ca[slot][wi];
        unsigned aw1 = (unsigned)cb[slot][wi];
        if (wi == 3 && cc < 6) {
          ca[slot] = *(const int4v*)(rp0 + (cc + 2) * 4);
          cb[slot] = *(const int4v*)(rp1 + (cc + 2) * 4);
        }
        // unpack 8 bits (byte g of word) -> bf16 0/1 pairs via integer smear
        uint4v ua, ub;
        #pragma unroll
        for (int q = 0; q < 4; ++q) {
          unsigned t0 = (aw0 >> (gb + 2 * q)) & 3u;
          unsigned t1 = (aw1 >> (gb + 2 * q)) & 3u;
          ua[q] = ((t0 * 0x8001u) & 0x00010001u) * 0x3F80u;
          ub[q] = ((t1 * 0x8001u) & 0x00010001u) * 0x3F80u;
        }
        short8 a0 = __builtin_bit_cast(short8, ua);
        short8 a1 = __builtin_bit_cast(short8, ub);
        short8 q0 = *(short8*)(smem + (basep[0] ^ (s * 64)));
        short8 q1 = *(short8*)(smem + (basep[1] ^ (s * 64)));
        acc[0][0] = __builtin_amdgcn_mfma_f32_16x16x32_bf16(a0, q0, acc[0][0], 0, 0, 0);
        acc[0][1] = __builtin_amdgcn_mfma_f32_16x16x32_bf16(a0, q1, acc[0][1], 0, 0, 0);
        acc[1][0] = __builtin_amdgcn_mfma_f32_16x16x32_bf16(a1, q0, acc[1][0], 0, 0, 0);
        acc[1][1] = __builtin_amdgcn_mfma_f32_16x16x32_bf16(a1, q1, acc[1][1], 0, 0, 0);
      }

      // split-K reduce (2-way): km1 writes, km0 adds + LIF epilogue
      __syncthreads();
      if (km == 1) {
        #pragma unroll
        for (int mi = 0; mi < 2; ++mi)
          #pragma unroll
          for (int ni = 0; ni < 2; ++ni)
            *(f32x4*)&scratch[(((wm * 2 + mi) * 2 + ni) * 256 + l * 4)] = acc[mi][ni];
      }
      __syncthreads();
      if (km == 0) {
        unsigned long long bal[2][2][4];
        #pragma unroll
        for (int mi = 0; mi < 2; ++mi)
          #pragma unroll
          for (int ni = 0; ni < 2; ++ni) {
            f32x4 a4 = acc[mi][ni] +
                       *(f32x4*)&scratch[(((wm * 2 + mi) * 2 + ni) * 256 + l * 4)];
            #pragma unroll
            for (int j = 0; j < 4; ++j) {
              float curv = a4[j] + bv2[ni];
              float mo = memb[mi][ni][j];
              float mn = 0.9f * mo + curv - ((mo > 1.f) ? 1.f : 0.f);
              memb[mi][ni][j] = mn;
              bool spike = (mn > 1.f);
              if (role == 2) {
                if (spike) osum[mi][ni][j] += 1.f;
              } else {
                bal[mi][ni][j] = __ballot((int)spike);
              }
            }
          }
        if (role < 2 && c16 == 0) {
          #pragma unroll
          for (int mi = 0; mi < 2; ++mi)
            #pragma unroll
            for (int j = 0; j < 4; ++j) {
              int r = wm * 32 + mi * 16 + g * 4 + j;
              unsigned w0 = (unsigned)((bal[mi][0][j] >> (g * 16)) & 0xFFFFull);
              unsigned w1 = (unsigned)((bal[mi][1][j] >> (g * 16)) & 0xFFFFull);
              soutb[r * 64 + (n0c >> 5)] = w0 | (w1 << 16);
            }
        }
      }
    }

    if (p < TT + 2) gbar(flags, gen);
  }

  // ---- final: store output spike sums (covers every (r, c<100) exactly once)
  if (role == 2 && km == 0) {
    #pragma unroll
    for (int mi = 0; mi < 2; ++mi)
      #pragma unroll
      for (int ni = 0; ni < 2; ++ni) {
        int colg = n0c + ni * 16 + c16;
        if (colg < CC) {
          #pragma unroll
          for (int j = 0; j < 4; ++j)
            outsum[(wm * 32 + mi * 16 + g * 4 + j) * CC + colg] = osum[mi][ni][j];
        }
      }
  }
}

extern "C" void kernel_launch(void* const* d_in, const int* in_sizes, int n_in,
                              void* d_out, int out_size, void* d_ws, size_t ws_size,
                              hipStream_t stream)
{
  const float* x  = (const float*)d_in[0];
  const float* W1 = (const float*)d_in[1];
  const float* b1 = (const float*)d_in[2];
  const float* W2 = (const float*)d_in[3];
  const float* b2 = (const float*)d_in[4];
  const float* W3 = (const float*)d_in[5];
  const float* b3 = (const float*)d_in[6];
  const float* Wo = (const float*)d_in[7];
  const float* bo = (const float*)d_in[8];
  float* out = (float*)d_out;

  // ws layout
  unsigned* flags = (unsigned*)d_ws;              // 8192 u32 (132 used, stride 32)
  unsigned* s1bits = flags + 8192;                // 2 * 128 * 64 u32 each
  unsigned* s2bits = s1bits + 2 * BB * 64;
  unsigned* s3bits = s2bits + 2 * BB * 64;
  unsigned short* Wt1 = (unsigned short*)(s3bits + 2 * BB * 64);   // 2048x2048
  unsigned short* cur1 = Wt1 + (size_t)HH * HH;                    // 12800x2048

  hipFuncSetAttribute((const void*)snn_persist,
                      hipFuncAttributeMaxDynamicSharedMemorySize, 147456);

  hipLaunchKernelGGL(init_kernel, dim3(64), dim3(256), 0, stream,
                     flags, 8192, out, BB * CC);
  hipLaunchKernelGGL(transpose_cvt, dim3(64, 64), dim3(32, 8), 0, stream, W1, Wt1);
  hipLaunchKernelGGL(gemm_big, dim3(HH / 64, (TT * BB) / 128), dim3(256), 0, stream,
                     x, Wt1, b1, cur1);
  hipLaunchKernelGGL(snn_persist, dim3(NBLK), dim3(512), 147456, stream,
                     cur1, W2, b2, W3, b3, Wo, bo,
                     s1bits, s2bits, s3bits, out, flags);
}

// Round 7
// 1406.731 us; speedup vs baseline: 14.9951x; 1.7612x over previous
//
#include <hip/hip_runtime.h>

typedef short short8 __attribute__((ext_vector_type(8)));
typedef float f32x4 __attribute__((ext_vector_type(4)));
typedef int int4v __attribute__((ext_vector_type(4)));

#define TT 100
#define BB 128
#define HH 2048
#define CC 100
#define NBLK 132
#define CHUNK 4
#define NCH (TT / CHUNK)       // 25 chunks
#define NPHASE (NCH + 3)       // 28 phases
#define SLOTW 8192             // u32 per step-slot: 128 rows x 64 words

__device__ inline unsigned short f2bf(float f) {
  unsigned u = __float_as_uint(f);
  return (unsigned short)((u + 0x7FFF + ((u >> 16) & 1)) >> 16);  // RNE
}
__device__ inline float bf2f(unsigned short b) {
  return __uint_as_float((unsigned)b << 16);
}

// W[k][n] fp32 (2048x2048) -> Wt[n][k] bf16 bits (for gemm_big / W1 only)
__global__ __launch_bounds__(256) void transpose_cvt(
    const float* __restrict__ W, unsigned short* __restrict__ Wt)
{
  __shared__ float t[32][33];
  int n0 = blockIdx.x * 32, k0 = blockIdx.y * 32;
  int tx = threadIdx.x, ty = threadIdx.y;   // (32,8)
  #pragma unroll
  for (int j = 0; j < 4; ++j)
    t[ty + 8 * j][tx] = W[(size_t)(k0 + ty + 8 * j) * HH + n0 + tx];
  __syncthreads();
  #pragma unroll
  for (int j = 0; j < 4; ++j)
    Wt[(size_t)(n0 + ty + 8 * j) * HH + k0 + tx] = f2bf(t[tx][ty + 8 * j]);
}

// Hoisted layer-1 GEMM: cur1[12800 x 2048] = x(fp32) @ W1 + b1, bf16 out.
__global__ __launch_bounds__(256) void gemm_big(
    const float* __restrict__ A, const unsigned short* __restrict__ Wt,
    const float* __restrict__ bias, unsigned short* __restrict__ cur)
{
  __shared__ unsigned short As[128 * 128];   // 32KB
  __shared__ unsigned short Bs[64 * 128];    // 16KB
  const int tid = threadIdx.x;
  const int w = tid >> 6, l = tid & 63;
  const int wm = w & 1, wn = w >> 1;
  const int c16 = l & 15, g = l >> 4;
  const int n0 = blockIdx.x * 64, m0 = blockIdx.y * 128;
  f32x4 acc[4][2] = {};

  for (int k0 = 0; k0 < 2048; k0 += 128) {
    #pragma unroll
    for (int i = 0; i < 8; ++i) {
      int gg = tid + i * 256;
      int r = gg >> 4, gi = gg & 15;
      int kb = (gi * 16) ^ ((r & 7) << 4);
      const float* src = A + (size_t)(m0 + r) * HH + k0 + (kb >> 1);
      float4 f0 = *(const float4*)src, f1 = *(const float4*)(src + 4);
      short8 pv;
      pv[0] = (short)f2bf(f0.x); pv[1] = (short)f2bf(f0.y);
      pv[2] = (short)f2bf(f0.z); pv[3] = (short)f2bf(f0.w);
      pv[4] = (short)f2bf(f1.x); pv[5] = (short)f2bf(f1.y);
      pv[6] = (short)f2bf(f1.z); pv[7] = (short)f2bf(f1.w);
      *(int4v*)((char*)As + r * 256 + kb) = *(int4v*)&pv;
    }
    #pragma unroll
    for (int i = 0; i < 4; ++i) {
      int gg = tid + i * 256;
      int r = gg >> 4, gi = gg & 15;
      int kb = (gi * 16) ^ ((r & 7) << 4);
      const char* bsrc = (const char*)(Wt + (size_t)(n0 + r) * HH + k0) + kb;
      *(int4v*)((char*)Bs + r * 256 + kb) = *(const int4v*)bsrc;
    }
    __syncthreads();
    #pragma unroll
    for (int kk = 0; kk < 4; ++kk) {
      int koff = (kk * 4 + g) * 16;
      short8 a[4], b[2];
      #pragma unroll
      for (int mi = 0; mi < 4; ++mi) {
        int mr = wm * 64 + mi * 16 + c16;
        a[mi] = *(short8*)((char*)As + mr * 256 + (koff ^ ((mr & 7) << 4)));
      }
      #pragma unroll
      for (int ni = 0; ni < 2; ++ni) {
        int nr = wn * 32 + ni * 16 + c16;
        b[ni] = *(short8*)((char*)Bs + nr * 256 + (koff ^ ((nr & 7) << 4)));
      }
      #pragma unroll
      for (int mi = 0; mi < 4; ++mi)
        #pragma unroll
        for (int ni = 0; ni < 2; ++ni)
          acc[mi][ni] = __builtin_amdgcn_mfma_f32_16x16x32_bf16(
              a[mi], b[ni], acc[mi][ni], 0, 0, 0);
    }
    __syncthreads();
  }
  #pragma unroll
  for (int mi = 0; mi < 4; ++mi)
    #pragma unroll
    for (int ni = 0; ni < 2; ++ni) {
      int col = n0 + wn * 32 + ni * 16 + c16;
      int rbase = m0 + wm * 64 + mi * 16 + g * 4;
      float bv = bias[col];
      #pragma unroll
      for (int j = 0; j < 4; ++j)
        cur[(size_t)(rbase + j) * HH + col] = f2bf(acc[mi][ni][j] + bv);
    }
}

__global__ void init_kernel(unsigned* flags, int n)
{
  int i = blockIdx.x * blockDim.x + threadIdx.x;
  int stride = gridDim.x * blockDim.x;
  for (int j = i; j < n; j += stride) flags[j] = 0u;
}

// Symmetric flag-array grid barrier (round-4/6-proven orderings, bounded spin).
__device__ inline void gbar(unsigned* flags, unsigned gen)
{
  __syncthreads();
  if (threadIdx.x == 0) {
    __threadfence();
    __hip_atomic_store(&flags[blockIdx.x * 32], gen, __ATOMIC_RELEASE,
                       __HIP_MEMORY_SCOPE_AGENT);
  }
  if (threadIdx.x < NBLK) {
    int guard = 0;
    while (__hip_atomic_load(&flags[threadIdx.x * 32], __ATOMIC_ACQUIRE,
                             __HIP_MEMORY_SCOPE_AGENT) < gen) {
      __builtin_amdgcn_s_sleep(2);
      if (++guard > (1 << 22)) break;   // fail loud (wrong absmax), never hang
    }
  }
  __syncthreads();
}

// half-position permutation: k-half kappa stored at p so that consumer lane
// (km,g) reads its 8 s-steps as ONE contiguous 16B chunk.
// p = km*32 + g*8 + s  <->  kappa = km*32 + s*4 + g.
// For even kappa = 2w:  p0 = (w>>4)*32 + (w&1)*16 + ((w&15)>>1),  p1 = p0 + 8.

// Persistent SNN: 132 blocks x 512 thr (8 waves = 4 K-quarters x 2 row-halves).
// Blocks 0..63 layer2, 64..127 layer3, 128..131 out (32 cols each).
// Weights quantized per-column to i8, held in REGISTERS (Breg). Spikes as
// 1-bit masks in per-step slots (permuted half layout). Membranes in regs.
// CHUNK=4 steps per phase -> 28 phases / 27 grid barriers.
__global__ __launch_bounds__(512, 2) void snn_persist(
    const unsigned short* __restrict__ cur1,
    const float* __restrict__ W2, const float* __restrict__ b2,
    const float* __restrict__ W3, const float* __restrict__ b3,
    const float* __restrict__ Wo, const float* __restrict__ bo,
    unsigned* __restrict__ s1b, unsigned* __restrict__ s2b,
    unsigned* __restrict__ s3b,
    float* __restrict__ outsum, unsigned* __restrict__ flags)
{
  __shared__ int sred[12288];        // 48KB: 6 regions x 512 int4v (split-K)
  __shared__ float smax[32][33];
  __shared__ float sscale[32];
  __shared__ float srscale[32];

  const int blk = blockIdx.x, tid = threadIdx.x;
  const int w = tid >> 6, l = tid & 63;
  const int km = w >> 1, wm = w & 1;
  const int c16 = l & 15, g = l >> 4;

  int role, n0c, ldw;
  const float *Wsrc, *bias;
  if (blk < 64)       { role = 0; Wsrc = W2; bias = b2; ldw = HH; n0c = blk * 32; }
  else if (blk < 128) { role = 1; Wsrc = W3; bias = b3; ldw = HH; n0c = (blk - 64) * 32; }
  else                { role = 2; Wsrc = Wo; bias = bo; ldw = CC; n0c = (blk - 128) * 32; }

  int cols[2]; bool valid[2]; float bv2[2];
  #pragma unroll
  for (int ni = 0; ni < 2; ++ni) {
    cols[ni] = n0c + ni * 16 + c16;
    valid[ni] = (role != 2) || (cols[ni] < CC);
    bv2[ni] = valid[ni] ? bias[cols[ni]] : 0.f;
  }

  // ---- pass 1: per-column absmax over this lane's MFMA slice ----
  float mx[2] = {0.f, 0.f};
  #pragma unroll
  for (int ni = 0; ni < 2; ++ni)
    #pragma unroll
    for (int s = 0; s < 8; ++s) {
      int kb = km * 512 + s * 64 + g * 16;
      #pragma unroll
      for (int e = 0; e < 16; ++e) {
        float v = valid[ni] ? Wsrc[(size_t)(kb + e) * ldw + cols[ni]] : 0.f;
        mx[ni] = fmaxf(mx[ni], fabsf(v));
      }
    }
  smax[c16][w * 4 + g] = mx[0];
  smax[c16 + 16][w * 4 + g] = mx[1];
  __syncthreads();
  if (tid < 32) {
    float m = 0.f;
    #pragma unroll
    for (int i = 0; i < 32; ++i) m = fmaxf(m, smax[tid][i]);
    sscale[tid] = m * (1.f / 127.f);
    srscale[tid] = (m > 0.f) ? (127.f / m) : 0.f;
  }
  __syncthreads();
  float scl[2], rsc[2];
  #pragma unroll
  for (int ni = 0; ni < 2; ++ni) {
    scl[ni] = sscale[c16 + ni * 16];
    rsc[ni] = srscale[c16 + ni * 16];
  }

  // ---- pass 2: quantize into register-resident B fragments ----
  int4v Breg[2][8];
  #pragma unroll
  for (int ni = 0; ni < 2; ++ni)
    #pragma unroll
    for (int s = 0; s < 8; ++s) {
      int4v q = {0, 0, 0, 0};
      int kb = km * 512 + s * 64 + g * 16;
      #pragma unroll
      for (int e = 0; e < 16; ++e) {
        float v = valid[ni] ? Wsrc[(size_t)(kb + e) * ldw + cols[ni]] : 0.f;
        int qi = (int)rintf(v * rsc[ni]);
        qi = qi > 127 ? 127 : (qi < -127 ? -127 : qi);
        q[e >> 2] |= (qi & 0xFF) << ((e & 3) * 8);
      }
      Breg[ni][s] = q;
    }

  const int wblk = n0c >> 5;
  const int pp0 = ((wblk >> 4) << 5) + ((wblk & 1) << 4) + ((wblk & 15) >> 1);

  f32x4 m1reg = {0.f, 0.f, 0.f, 0.f};
  f32x4 memb[4][2] = {};
  f32x4 osum[4][2] = {};

  for (int p = 0; p < NPHASE; ++p) {
    // ---- layer-1 LIF (row = blk) for CHUNK steps; shfl-pack to bit slots
    if (blk < BB && p < NCH) {
      const int tb = p * CHUNK;
      unsigned cwa[CHUNK], cwb[CHUNK];
      #pragma unroll
      for (int st = 0; st < CHUNK; ++st) {
        const unsigned* cp = (const unsigned*)(cur1 +
            ((size_t)(tb + st) * BB + blk) * HH) + tid * 2;
        cwa[st] = cp[0]; cwb[st] = cp[1];
      }
      #pragma unroll
      for (int st = 0; st < CHUNK; ++st) {
        float cv[4] = { bf2f((unsigned short)(cwa[st] & 0xFFFF)),
                        bf2f((unsigned short)(cwa[st] >> 16)),
                        bf2f((unsigned short)(cwb[st] & 0xFFFF)),
                        bf2f((unsigned short)(cwb[st] >> 16)) };
        unsigned nib = 0;
        #pragma unroll
        for (int j = 0; j < 4; ++j) {
          float mo = m1reg[j];
          float mn = 0.9f * mo + cv[j] - ((mo > 1.f) ? 1.f : 0.f);
          m1reg[j] = mn;
          nib |= (mn > 1.f ? 1u : 0u) << j;
        }
        unsigned v = nib;
        v |= ((unsigned)__shfl_xor((int)v, 1)) << 4;
        v |= ((unsigned)__shfl_xor((int)v, 2)) << 8;
        v |= ((unsigned)__shfl_xor((int)v, 4)) << 16;
        if ((tid & 7) == 0) {
          int w8 = tid >> 3;
          int q0 = ((w8 >> 4) << 5) + ((w8 & 1) << 4) + ((w8 & 15) >> 1);
          unsigned short* so = (unsigned short*)(s1b + (size_t)(tb + st) * SLOTW)
                               + blk * 128;
          so[q0] = (unsigned short)(v & 0xFFFF);
          so[q0 + 8] = (unsigned short)(v >> 16);
        }
      }
    }

    // ---- GEMM+LIF: role r processes chunk p-1-r (4 steps)
    int tch = p - 1 - role;
    if (tch >= 0 && tch < NCH) {
      const unsigned* layIn = role == 0 ? s1b : role == 1 ? s2b : s3b;
      unsigned* layOut = role == 0 ? s2b : s3b;
      #pragma unroll 1
      for (int st = 0; st < CHUNK; ++st) {
        int t = tch * CHUNK + st;
        const char* sb = (const char*)(layIn + (size_t)t * SLOTW);
        int4v Ab[4];
        #pragma unroll
        for (int mi = 0; mi < 4; ++mi)
          Ab[mi] = *(const int4v*)(sb + (wm * 64 + mi * 16 + c16) * 256 +
                                   km * 64 + g * 16);
        int4v acc[4][2] = {};
        #pragma unroll
        for (int s = 0; s < 8; ++s) {
          #pragma unroll
          for (int mi = 0; mi < 4; ++mi) {
            unsigned word = (unsigned)Ab[mi][s >> 1];
            unsigned h = (s & 1) ? (word >> 16) : (word & 0xFFFFu);
            int4v af;
            af[0] = (int)(((h & 15u) * 0x204081u) & 0x01010101u);
            af[1] = (int)((((h >> 4) & 15u) * 0x204081u) & 0x01010101u);
            af[2] = (int)((((h >> 8) & 15u) * 0x204081u) & 0x01010101u);
            af[3] = (int)(((h >> 12) * 0x204081u) & 0x01010101u);
            acc[mi][0] = __builtin_amdgcn_mfma_i32_16x16x64_i8(
                af, Breg[0][s], acc[mi][0], 0, 0, 0);
            acc[mi][1] = __builtin_amdgcn_mfma_i32_16x16x64_i8(
                af, Breg[1][s], acc[mi][1], 0, 0, 0);
          }
        }
        __syncthreads();
        if (km > 0) {
          int rbase = ((km - 1) * 2 + wm) * 512;
          #pragma unroll
          for (int mi = 0; mi < 4; ++mi)
            #pragma unroll
            for (int ni = 0; ni < 2; ++ni)
              *(int4v*)&sred[(rbase + (mi * 2 + ni) * 64 + l) * 4] = acc[mi][ni];
        }
        __syncthreads();
        if (km == 0) {
          #pragma unroll
          for (int mi = 0; mi < 4; ++mi) {
            unsigned long long bal[2][4];
            #pragma unroll
            for (int ni = 0; ni < 2; ++ni) {
              int4v tot = acc[mi][ni];
              #pragma unroll
              for (int r = 0; r < 3; ++r)
                tot = tot + *(int4v*)&sred[((r * 2 + wm) * 512 +
                                            (mi * 2 + ni) * 64 + l) * 4];
              #pragma unroll
              for (int j = 0; j < 4; ++j) {
                float curv = (float)tot[j] * scl[ni] + bv2[ni];
                float mo = memb[mi][ni][j];
                float mn = 0.9f * mo + curv - ((mo > 1.f) ? 1.f : 0.f);
                memb[mi][ni][j] = mn;
                bool spike = (mn > 1.f);
                if (role == 2) {
                  if (spike) osum[mi][ni][j] += 1.f;
                  bal[ni][j] = 0;
                } else {
                  bal[ni][j] = __ballot((int)spike);
                }
              }
            }
            if (role < 2 && c16 == 0) {
              unsigned short* so = (unsigned short*)(layOut + (size_t)t * SLOTW);
              #pragma unroll
              for (int j = 0; j < 4; ++j) {
                int row = wm * 64 + mi * 16 + g * 4 + j;
                so[row * 128 + pp0] =
                    (unsigned short)((bal[0][j] >> (g * 16)) & 0xFFFFull);
                so[row * 128 + pp0 + 8] =
                    (unsigned short)((bal[1][j] >> (g * 16)) & 0xFFFFull);
              }
            }
          }
        }
      }
    }

    if (p < NPHASE - 1) gbar(flags, (unsigned)(p + 1));
  }

  // ---- final: write output spike sums (each (r, c<100) exactly once)
  if (role == 2 && km == 0) {
    #pragma unroll
    for (int mi = 0; mi < 4; ++mi)
      #pragma unroll
      for (int ni = 0; ni < 2; ++ni) {
        int colg = n0c + ni * 16 + c16;
        if (colg < CC) {
          #pragma unroll
          for (int j = 0; j < 4; ++j)
            outsum[(wm * 64 + mi * 16 + g * 4 + j) * CC + colg] = osum[mi][ni][j];
        }
      }
  }
}

extern "C" void kernel_launch(void* const* d_in, const int* in_sizes, int n_in,
                              void* d_out, int out_size, void* d_ws, size_t ws_size,
                              hipStream_t stream)
{
  const float* x  = (const float*)d_in[0];
  const float* W1 = (const float*)d_in[1];
  const float* b1 = (const float*)d_in[2];
  const float* W2 = (const float*)d_in[3];
  const float* b2 = (const float*)d_in[4];
  const float* W3 = (const float*)d_in[5];
  const float* b3 = (const float*)d_in[6];
  const float* Wo = (const float*)d_in[7];
  const float* bo = (const float*)d_in[8];
  float* out = (float*)d_out;

  // ws layout
  unsigned* flags = (unsigned*)d_ws;                       // 8192 u32
  unsigned* s1b = flags + 8192;                            // TT*SLOTW u32 each
  unsigned* s2b = s1b + (size_t)TT * SLOTW;
  unsigned* s3b = s2b + (size_t)TT * SLOTW;
  unsigned short* Wt1 = (unsigned short*)(s3b + (size_t)TT * SLOTW);  // 2048^2
  unsigned short* cur1 = Wt1 + (size_t)HH * HH;            // 12800 x 2048 bf16

  hipLaunchKernelGGL(init_kernel, dim3(32), dim3(256), 0, stream, flags, 8192);
  hipLaunchKernelGGL(transpose_cvt, dim3(64, 64), dim3(32, 8), 0, stream, W1, Wt1);
  hipLaunchKernelGGL(gemm_big, dim3(HH / 64, (TT * BB) / 128), dim3(256), 0, stream,
                     x, Wt1, b1, cur1);
  hipLaunchKernelGGL(snn_persist, dim3(NBLK), dim3(512), 0, stream,
                     cur1, W2, b2, W3, b3, Wo, bo,
                     s1b, s2b, s3b, out, flags);
}

// Round 8
// 855.822 us; speedup vs baseline: 24.6477x; 1.6437x over previous
//
#include <hip/hip_runtime.h>

typedef short short8 __attribute__((ext_vector_type(8)));
typedef float f32x4 __attribute__((ext_vector_type(4)));
typedef int int4v __attribute__((ext_vector_type(4)));

#define TT 100
#define BB 128
#define HH 2048
#define CC 100
#define NBLK 256
#define CHUNK 10
#define NCH (TT / CHUNK)        // 10 chunks
#define NPHASE (NCH + 3)        // 13 phases
#define SLOTW 8192              // u32 per step-slot: 128 rows x 64 words

__device__ inline unsigned short f2bf(float f) {
  unsigned u = __float_as_uint(f);
  return (unsigned short)((u + 0x7FFF + ((u >> 16) & 1)) >> 16);  // RNE
}
__device__ inline float bf2f(unsigned short b) {
  return __uint_as_float((unsigned)b << 16);
}

// W[k][n] fp32 (2048x2048) -> Wt[n][k] bf16 bits (for gemm_big / W1 only)
__global__ __launch_bounds__(256) void transpose_cvt(
    const float* __restrict__ W, unsigned short* __restrict__ Wt)
{
  __shared__ float t[32][33];
  int n0 = blockIdx.x * 32, k0 = blockIdx.y * 32;
  int tx = threadIdx.x, ty = threadIdx.y;   // (32,8)
  #pragma unroll
  for (int j = 0; j < 4; ++j)
    t[ty + 8 * j][tx] = W[(size_t)(k0 + ty + 8 * j) * HH + n0 + tx];
  __syncthreads();
  #pragma unroll
  for (int j = 0; j < 4; ++j)
    Wt[(size_t)(n0 + ty + 8 * j) * HH + k0 + tx] = f2bf(t[tx][ty + 8 * j]);
}

// x fp32 -> bf16 (row-major, same layout)
__global__ __launch_bounds__(512) void cvt_x(
    const float* __restrict__ x, unsigned short* __restrict__ xb, long n8)
{
  long i = (long)blockIdx.x * blockDim.x + threadIdx.x;
  if (i >= n8) return;
  const float4* p = (const float4*)x + i * 2;
  float4 a = p[0], b = p[1];
  short8 pv;
  pv[0] = (short)f2bf(a.x); pv[1] = (short)f2bf(a.y);
  pv[2] = (short)f2bf(a.z); pv[3] = (short)f2bf(a.w);
  pv[4] = (short)f2bf(b.x); pv[5] = (short)f2bf(b.y);
  pv[6] = (short)f2bf(b.z); pv[7] = (short)f2bf(b.w);
  *(short8*)(xb + i * 8) = pv;
}

// Hoisted layer-1 GEMM, A already bf16: cur1 = xb @ W1 + b1 (bf16 out).
__global__ __launch_bounds__(256) void gemm_big_bf16(
    const unsigned short* __restrict__ Ab, const unsigned short* __restrict__ Wt,
    const float* __restrict__ bias, unsigned short* __restrict__ cur)
{
  __shared__ unsigned short As[128 * 128];   // 32KB
  __shared__ unsigned short Bs[64 * 128];    // 16KB
  const int tid = threadIdx.x;
  const int w = tid >> 6, l = tid & 63;
  const int wm = w & 1, wn = w >> 1;
  const int c16 = l & 15, g = l >> 4;
  const int n0 = blockIdx.x * 64, m0 = blockIdx.y * 128;
  f32x4 acc[4][2] = {};

  for (int k0 = 0; k0 < 2048; k0 += 128) {
    #pragma unroll
    for (int i = 0; i < 8; ++i) {
      int gg = tid + i * 256;
      int r = gg >> 4, gi = gg & 15;
      int kb = (gi * 16) ^ ((r & 7) << 4);
      const char* src = (const char*)(Ab + (size_t)(m0 + r) * HH + k0) + kb;
      *(int4v*)((char*)As + r * 256 + kb) = *(const int4v*)src;
    }
    #pragma unroll
    for (int i = 0; i < 4; ++i) {
      int gg = tid + i * 256;
      int r = gg >> 4, gi = gg & 15;
      int kb = (gi * 16) ^ ((r & 7) << 4);
      const char* bsrc = (const char*)(Wt + (size_t)(n0 + r) * HH + k0) + kb;
      *(int4v*)((char*)Bs + r * 256 + kb) = *(const int4v*)bsrc;
    }
    __syncthreads();
    #pragma unroll
    for (int kk = 0; kk < 4; ++kk) {
      int koff = (kk * 4 + g) * 16;
      short8 a[4], b[2];
      #pragma unroll
      for (int mi = 0; mi < 4; ++mi) {
        int mr = wm * 64 + mi * 16 + c16;
        a[mi] = *(short8*)((char*)As + mr * 256 + (koff ^ ((mr & 7) << 4)));
      }
      #pragma unroll
      for (int ni = 0; ni < 2; ++ni) {
        int nr = wn * 32 + ni * 16 + c16;
        b[ni] = *(short8*)((char*)Bs + nr * 256 + (koff ^ ((nr & 7) << 4)));
      }
      #pragma unroll
      for (int mi = 0; mi < 4; ++mi)
        #pragma unroll
        for (int ni = 0; ni < 2; ++ni)
          acc[mi][ni] = __builtin_amdgcn_mfma_f32_16x16x32_bf16(
              a[mi], b[ni], acc[mi][ni], 0, 0, 0);
    }
    __syncthreads();
  }
  #pragma unroll
  for (int mi = 0; mi < 4; ++mi)
    #pragma unroll
    for (int ni = 0; ni < 2; ++ni) {
      int col = n0 + wn * 32 + ni * 16 + c16;
      int rbase = m0 + wm * 64 + mi * 16 + g * 4;
      float bv = bias[col];
      #pragma unroll
      for (int j = 0; j < 4; ++j)
        cur[(size_t)(rbase + j) * HH + col] = f2bf(acc[mi][ni][j] + bv);
    }
}

// Fallback (ws too small for xb): fp32 A with inline cvt — round-7-proven.
__global__ __launch_bounds__(256) void gemm_big_f32(
    const float* __restrict__ A, const unsigned short* __restrict__ Wt,
    const float* __restrict__ bias, unsigned short* __restrict__ cur)
{
  __shared__ unsigned short As[128 * 128];
  __shared__ unsigned short Bs[64 * 128];
  const int tid = threadIdx.x;
  const int w = tid >> 6, l = tid & 63;
  const int wm = w & 1, wn = w >> 1;
  const int c16 = l & 15, g = l >> 4;
  const int n0 = blockIdx.x * 64, m0 = blockIdx.y * 128;
  f32x4 acc[4][2] = {};

  for (int k0 = 0; k0 < 2048; k0 += 128) {
    #pragma unroll
    for (int i = 0; i < 8; ++i) {
      int gg = tid + i * 256;
      int r = gg >> 4, gi = gg & 15;
      int kb = (gi * 16) ^ ((r & 7) << 4);
      const float* src = A + (size_t)(m0 + r) * HH + k0 + (kb >> 1);
      float4 f0 = *(const float4*)src, f1 = *(const float4*)(src + 4);
      short8 pv;
      pv[0] = (short)f2bf(f0.x); pv[1] = (short)f2bf(f0.y);
      pv[2] = (short)f2bf(f0.z); pv[3] = (short)f2bf(f0.w);
      pv[4] = (short)f2bf(f1.x); pv[5] = (short)f2bf(f1.y);
      pv[6] = (short)f2bf(f1.z); pv[7] = (short)f2bf(f1.w);
      *(int4v*)((char*)As + r * 256 + kb) = *(int4v*)&pv;
    }
    #pragma unroll
    for (int i = 0; i < 4; ++i) {
      int gg = tid + i * 256;
      int r = gg >> 4, gi = gg & 15;
      int kb = (gi * 16) ^ ((r & 7) << 4);
      const char* bsrc = (const char*)(Wt + (size_t)(n0 + r) * HH + k0) + kb;
      *(int4v*)((char*)Bs + r * 256 + kb) = *(const int4v*)bsrc;
    }
    __syncthreads();
    #pragma unroll
    for (int kk = 0; kk < 4; ++kk) {
      int koff = (kk * 4 + g) * 16;
      short8 a[4], b[2];
      #pragma unroll
      for (int mi = 0; mi < 4; ++mi) {
        int mr = wm * 64 + mi * 16 + c16;
        a[mi] = *(short8*)((char*)As + mr * 256 + (koff ^ ((mr & 7) << 4)));
      }
      #pragma unroll
      for (int ni = 0; ni < 2; ++ni) {
        int nr = wn * 32 + ni * 16 + c16;
        b[ni] = *(short8*)((char*)Bs + nr * 256 + (koff ^ ((nr & 7) << 4)));
      }
      #pragma unroll
      for (int mi = 0; mi < 4; ++mi)
        #pragma unroll
        for (int ni = 0; ni < 2; ++ni)
          acc[mi][ni] = __builtin_amdgcn_mfma_f32_16x16x32_bf16(
              a[mi], b[ni], acc[mi][ni], 0, 0, 0);
    }
    __syncthreads();
  }
  #pragma unroll
  for (int mi = 0; mi < 4; ++mi)
    #pragma unroll
    for (int ni = 0; ni < 2; ++ni) {
      int col = n0 + wn * 32 + ni * 16 + c16;
      int rbase = m0 + wm * 64 + mi * 16 + g * 4;
      float bv = bias[col];
      #pragma unroll
      for (int j = 0; j < 4; ++j)
        cur[(size_t)(rbase + j) * HH + col] = f2bf(acc[mi][ni][j] + bv);
    }
}

__global__ void init_kernel(unsigned* flags, int n)
{
  int i = blockIdx.x * blockDim.x + threadIdx.x;
  int stride = gridDim.x * blockDim.x;
  for (int j = i; j < n; j += stride) flags[j] = 0u;
}

// Persistent SNN: 256 blocks x 512 thr. blk<128: L2 panel (16 cols) + L1-LIF
// row duty. blk>=128: L3 panel + sparse out-layer scan duty (row blk-128).
// Weights per-column i8 in registers; spikes = 1-bit masks in per-step slots
// (permuted-half layout); membranes in registers. CHUNK=10 -> 13 phases.
// Barrier: parallel release arrivals -> master(blk0) collects -> go release.
__global__ __launch_bounds__(512) void snn_persist(
    const unsigned short* __restrict__ cur1,
    const float* __restrict__ W2, const float* __restrict__ b2,
    const float* __restrict__ W3, const float* __restrict__ b3,
    const float* __restrict__ Wo, const float* __restrict__ bo,
    unsigned* __restrict__ s1b, unsigned* __restrict__ s2b,
    unsigned* __restrict__ s3b,
    float* __restrict__ outsum, unsigned* __restrict__ flags,
    unsigned* __restrict__ go)
{
  __shared__ int4v sred[6 * 256];              // 24KB split-K scratch
  __shared__ unsigned sow[CHUNK * 64];         // out-scan row bits
  __shared__ unsigned long long swm[CHUNK];    // nonzero-word masks
  __shared__ float smax[16][33];
  __shared__ float sscale[16];
  __shared__ float srscale[16];

  const int blk = blockIdx.x, tid = threadIdx.x;
  const int w = tid >> 6, l = tid & 63;
  const int km = w >> 1, wm = w & 1;           // 4-way K x 2-way rows
  const int c16 = l & 15, g = l >> 4;
  const bool isL2 = blk < 128;
  const int panel = blk & 127;
  const int n0c = panel * 16;
  const float* Wsrc = isL2 ? W2 : W3;
  const float* bias = isL2 ? b2 : b3;
  const int col = n0c + c16;

  // ---- quant pass 1: per-column absmax over lane slice
  float mx = 0.f;
  for (int s = 0; s < 8; ++s) {
    int kb = km * 512 + s * 64 + g * 16;
    #pragma unroll
    for (int e = 0; e < 16; ++e)
      mx = fmaxf(mx, fabsf(Wsrc[(size_t)(kb + e) * HH + col]));
  }
  smax[c16][w * 4 + g] = mx;
  __syncthreads();
  if (tid < 16) {
    float m = 0.f;
    #pragma unroll
    for (int i = 0; i < 32; ++i) m = fmaxf(m, smax[tid][i]);
    sscale[tid] = m * (1.f / 127.f);
    srscale[tid] = (m > 0.f) ? (127.f / m) : 0.f;
  }
  __syncthreads();
  const float scl = sscale[c16], rsc = srscale[c16];
  const float bv = bias[col];

  // ---- quant pass 2: register-resident i8 B fragments
  int4v Breg[8];
  for (int s = 0; s < 8; ++s) {
    int4v q = {0, 0, 0, 0};
    int kb = km * 512 + s * 64 + g * 16;
    #pragma unroll
    for (int e = 0; e < 16; ++e) {
      float v = Wsrc[(size_t)(kb + e) * HH + col];
      int qi = (int)rintf(v * rsc);
      qi = qi > 127 ? 127 : (qi < -127 ? -127 : qi);
      q[e >> 2] |= (qi & 0xFF) << ((e & 3) * 8);
    }
    Breg[s] = q;
  }

  // spike-bit store position for this block's 16-col half (kappa = panel)
  int ppos;
  {
    int wv = panel >> 1;
    ppos = ((wv >> 4) << 5) + ((wv & 1) << 4) + ((wv & 15) >> 1) +
           ((panel & 1) << 3);
  }

  f32x4 m1reg = {0.f, 0.f, 0.f, 0.f};
  f32x4 memb[4] = {};
  float memo = 0.f, osumo = 0.f;
  const float boc = (!isL2 && tid < CC) ? bo[tid] : 0.f;
  const int rowa = wm * 64 + c16;

  for (int p = 0; p < NPHASE; ++p) {
    // ---- L1-LIF duty (L2 blocks): row = blk, chunk p
    if (isL2 && p < NCH) {
      unsigned cw0[CHUNK], cw1[CHUNK];
      #pragma unroll
      for (int st = 0; st < CHUNK; ++st) {
        const unsigned* cp = (const unsigned*)(cur1 +
            ((size_t)(p * CHUNK + st) * BB + blk) * HH) + tid * 2;
        cw0[st] = cp[0]; cw1[st] = cp[1];
      }
      #pragma unroll
      for (int st = 0; st < CHUNK; ++st) {
        float cv[4] = { bf2f((unsigned short)(cw0[st] & 0xFFFF)),
                        bf2f((unsigned short)(cw0[st] >> 16)),
                        bf2f((unsigned short)(cw1[st] & 0xFFFF)),
                        bf2f((unsigned short)(cw1[st] >> 16)) };
        unsigned nib = 0;
        #pragma unroll
        for (int j = 0; j < 4; ++j) {
          float mo = m1reg[j];
          float mn = 0.9f * mo + cv[j] - ((mo > 1.f) ? 1.f : 0.f);
          m1reg[j] = mn;
          nib |= (mn > 1.f ? 1u : 0u) << j;
        }
        unsigned v = nib;
        v |= ((unsigned)__shfl_xor((int)v, 1)) << 4;
        v |= ((unsigned)__shfl_xor((int)v, 2)) << 8;
        v |= ((unsigned)__shfl_xor((int)v, 4)) << 16;
        if ((tid & 7) == 0) {
          int w8 = tid >> 3;
          int q0 = ((w8 >> 4) << 5) + ((w8 & 1) << 4) + ((w8 & 15) >> 1);
          unsigned short* so = (unsigned short*)(s1b +
              (size_t)(p * CHUNK + st) * SLOTW) + blk * 128;
          so[q0] = (unsigned short)(v & 0xFFFF);
          so[q0 + 8] = (unsigned short)(v >> 16);
        }
      }
    }

    // ---- GEMM+LIF duty: L2 does chunk p-1, L3 does chunk p-2
    int tch = p - (isL2 ? 1 : 2);
    if (tch >= 0 && tch < NCH) {
      const unsigned* sinb = isL2 ? s1b : s2b;
      unsigned* soutb = isL2 ? s2b : s3b;
      int4v A0[4], A1[4];
      {
        const char* sb = (const char*)(sinb + (size_t)(tch * CHUNK) * SLOTW);
        #pragma unroll
        for (int mi = 0; mi < 4; ++mi)
          A0[mi] = *(const int4v*)(sb + (rowa + mi * 16) * 256 + km * 64 + g * 16);
      }
      #pragma unroll 2
      for (int st = 0; st < CHUNK; ++st) {
        const int t = tch * CHUNK + st;
        int4v* Ac = (st & 1) ? A1 : A0;
        int4v* An = (st & 1) ? A0 : A1;
        if (st < CHUNK - 1) {
          const char* sb = (const char*)(sinb + (size_t)(t + 1) * SLOTW);
          #pragma unroll
          for (int mi = 0; mi < 4; ++mi)
            An[mi] = *(const int4v*)(sb + (rowa + mi * 16) * 256 + km * 64 + g * 16);
        }
        int4v acc[4] = {};
        #pragma unroll
        for (int s = 0; s < 8; ++s)
          #pragma unroll
          for (int mi = 0; mi < 4; ++mi) {
            unsigned word = (unsigned)Ac[mi][s >> 1];
            unsigned h = (s & 1) ? (word >> 16) : (word & 0xFFFFu);
            int4v af;
            af[0] = (int)(((h & 15u) * 0x204081u) & 0x01010101u);
            af[1] = (int)((((h >> 4) & 15u) * 0x204081u) & 0x01010101u);
            af[2] = (int)((((h >> 8) & 15u) * 0x204081u) & 0x01010101u);
            af[3] = (int)(((h >> 12) * 0x204081u) & 0x01010101u);
            acc[mi] = __builtin_amdgcn_mfma_i32_16x16x64_i8(
                af, Breg[s], acc[mi], 0, 0, 0);
          }
        __syncthreads();
        if (km > 0) {
          #pragma unroll
          for (int mi = 0; mi < 4; ++mi)
            sred[((km - 1) * 2 + wm) * 256 + mi * 64 + l] = acc[mi];
        }
        __syncthreads();
        if (km == 0) {
          #pragma unroll
          for (int mi = 0; mi < 4; ++mi) {
            int4v tot = acc[mi];
            #pragma unroll
            for (int r = 0; r < 3; ++r)
              tot = tot + sred[(r * 2 + wm) * 256 + mi * 64 + l];
            unsigned long long bal[4];
            #pragma unroll
            for (int j = 0; j < 4; ++j) {
              float curv = (float)tot[j] * scl + bv;
              float mo = memb[mi][j];
              float mn = 0.9f * mo + curv - ((mo > 1.f) ? 1.f : 0.f);
              memb[mi][j] = mn;
              bal[j] = __ballot((int)(mn > 1.f));
            }
            if (c16 == 0) {
              unsigned short* so = (unsigned short*)(soutb + (size_t)t * SLOTW);
              #pragma unroll
              for (int j = 0; j < 4; ++j) {
                int row = wm * 64 + mi * 16 + g * 4 + j;
                so[row * 128 + ppos] =
                    (unsigned short)((bal[j] >> (g * 16)) & 0xFFFFull);
              }
            }
          }
        }
      }
    }

    // ---- out-layer sparse scan duty (L3 blocks): row = blk-128, chunk p-3
    int oc = p - 3;
    if (!isL2 && oc >= 0 && oc < NCH) {
      int r = blk - 128;
      for (int i = tid; i < CHUNK * 64; i += 512)
        sow[i] = s3b[(size_t)(oc * CHUNK + (i >> 6)) * SLOTW + r * 64 + (i & 63)];
      __syncthreads();
      if (tid < CHUNK) {
        unsigned long long m = 0;
        for (int wd = 0; wd < 64; ++wd)
          if (sow[tid * 64 + wd]) m |= 1ull << wd;
        swm[tid] = m;
      }
      __syncthreads();
      if (tid < CC) {
        #pragma unroll 1
        for (int st = 0; st < CHUNK; ++st) {
          float curv = boc;
          unsigned long long m = swm[st];
          while (m) {
            int wd = (int)__ffsll((long long)m) - 1; m &= m - 1;
            unsigned wv2 = sow[st * 64 + wd];
            #pragma unroll
            for (int hf = 0; hf < 2; ++hf) {
              unsigned hv = hf ? (wv2 >> 16) : (wv2 & 0xFFFFu);
              int P = wd * 2 + hf;
              int kap = ((P >> 5) << 5) + ((P & 7) << 2) + ((P >> 3) & 3);
              while (hv) {
                int b = (int)__ffs(hv) - 1; hv &= hv - 1;
                curv += Wo[(size_t)(kap * 16 + b) * CC + tid];
              }
            }
          }
          float mo = memo;
          float mn = 0.9f * mo + curv - ((mo > 1.f) ? 1.f : 0.f);
          memo = mn;
          if (mn > 1.f) osumo += 1.f;
        }
      }
    }

    // ---- grid barrier (master-collect), proven orderings, bounded spins
    if (p < NPHASE - 1) {
      unsigned gen = (unsigned)(p + 1);
      __syncthreads();
      if (tid == 0)
        __hip_atomic_store(&flags[blk * 32], gen, __ATOMIC_RELEASE,
                           __HIP_MEMORY_SCOPE_AGENT);
      if (blk == 0) {
        if (tid < NBLK) {
          int guard = 0;
          while (__hip_atomic_load(&flags[tid * 32], __ATOMIC_ACQUIRE,
                                   __HIP_MEMORY_SCOPE_AGENT) < gen) {
            __builtin_amdgcn_s_sleep(2);
            if (++guard > (1 << 22)) break;
          }
        }
        __syncthreads();
        if (tid == 0)
          __hip_atomic_store(go, gen, __ATOMIC_RELEASE,
                             __HIP_MEMORY_SCOPE_AGENT);
      } else {
        if (tid == 0) {
          int guard = 0;
          while (__hip_atomic_load(go, __ATOMIC_ACQUIRE,
                                   __HIP_MEMORY_SCOPE_AGENT) < gen) {
            __builtin_amdgcn_s_sleep(4);
            if (++guard > (1 << 22)) break;
          }
        }
        __syncthreads();
      }
    }
  }

  if (!isL2 && tid < CC)
    outsum[(blk - 128) * CC + tid] = osumo;
}

extern "C" void kernel_launch(void* const* d_in, const int* in_sizes, int n_in,
                              void* d_out, int out_size, void* d_ws, size_t ws_size,
                              hipStream_t stream)
{
  const float* x  = (const float*)d_in[0];
  const float* W1 = (const float*)d_in[1];
  const float* b1 = (const float*)d_in[2];
  const float* W2 = (const float*)d_in[3];
  const float* b2 = (const float*)d_in[4];
  const float* W3 = (const float*)d_in[5];
  const float* b3 = (const float*)d_in[6];
  const float* Wo = (const float*)d_in[7];
  const float* bo = (const float*)d_in[8];
  float* out = (float*)d_out;

  // ws layout
  unsigned* flags = (unsigned*)d_ws;                       // 16384 u32 region
  unsigned* go = flags + 8192;
  unsigned* s1b = flags + 16384;                           // TT*SLOTW each
  unsigned* s2b = s1b + (size_t)TT * SLOTW;
  unsigned* s3b = s2b + (size_t)TT * SLOTW;
  unsigned short* Wt1 = (unsigned short*)(s3b + (size_t)TT * SLOTW);  // 2048^2
  unsigned short* cur1 = Wt1 + (size_t)HH * HH;            // 12800 x 2048 bf16
  unsigned short* xb = cur1 + (size_t)TT * BB * HH;        // 12800 x 2048 bf16
  size_t need_xb = (size_t)((char*)(xb + (size_t)TT * BB * HH) - (char*)d_ws);

  hipLaunchKernelGGL(init_kernel, dim3(32), dim3(256), 0, stream, flags, 16384);
  hipLaunchKernelGGL(transpose_cvt, dim3(64, 64), dim3(32, 8), 0, stream, W1, Wt1);
  if (ws_size >= need_xb) {
    long n8 = (long)TT * BB * HH / 8;
    hipLaunchKernelGGL(cvt_x, dim3((unsigned)((n8 + 511) / 512)), dim3(512),
                       0, stream, x, xb, n8);
    hipLaunchKernelGGL(gemm_big_bf16, dim3(HH / 64, (TT * BB) / 128), dim3(256),
                       0, stream, xb, Wt1, b1, cur1);
  } else {
    hipLaunchKernelGGL(gemm_big_f32, dim3(HH / 64, (TT * BB) / 128), dim3(256),
                       0, stream, x, Wt1, b1, cur1);
  }
  hipLaunchKernelGGL(snn_persist, dim3(NBLK), dim3(512), 0, stream,
                     cur1, W2, b2, W3, b3, Wo, bo,
                     s1b, s2b, s3b, out, flags, go);
}